// Round 4
// baseline (352.385 us; speedup 1.0000x reference)
//
#include <hip/hip_runtime.h>
#include <math.h>

#define NN 10000
#define EE 160000
#define EP 170000          // EE + NN self loops
#define NFEAT 256
#define NHID 128
#define NH 4
#define HF 512             // NH * NHID
#define NCLASS 40
#define FCOLS 1088         // 512 xh + 512 res + 8 attn + 56 pad

typedef __attribute__((ext_vector_type(8))) short bf8;     // 8 bf16 (4 VGPR) MFMA frag
typedef __attribute__((ext_vector_type(8))) unsigned short u16x8;
typedef __attribute__((ext_vector_type(4))) float f4;

__device__ __forceinline__ float leaky02(float x) { return x >= 0.0f ? x : 0.2f * x; }

__device__ __forceinline__ unsigned short f2bf(float f) {   // RNE
    unsigned u = __builtin_bit_cast(unsigned, f);
    unsigned r = (u + 0x7FFF + ((u >> 16) & 1)) >> 16;
    return (unsigned short)r;
}
__device__ __forceinline__ float bf2f(unsigned short h) {
    return __builtin_bit_cast(float, (unsigned)h << 16);
}

// ---------------- CSR build ----------------
__global__ __launch_bounds__(256)
void count_edges_k(const int* __restrict__ ei, int* __restrict__ cnt)
{
    int e = blockIdx.x * 256 + threadIdx.x;
    if (e >= EP) return;
    int d = (e < EE) ? ei[EE + e] : (e - EE);
    atomicAdd(&cnt[d], 1);
}

__global__ __launch_bounds__(256)
void scan_k(const int* __restrict__ cnt, int* __restrict__ row_ptr)
{
    __shared__ int sm[256];
    int t = threadIdx.x;
    int i0 = t * 40, i1 = min(i0 + 40, NN);
    int part = 0;
    for (int i = i0; i < i1; ++i) part += cnt[i];
    sm[t] = part;
    __syncthreads();
    for (int off = 1; off < 256; off <<= 1) {
        int v = (t >= off) ? sm[t - off] : 0;
        __syncthreads();
        sm[t] += v;
        __syncthreads();
    }
    int run = sm[t] - part;             // exclusive prefix
    for (int i = i0; i < i1; ++i) { row_ptr[i] = run; run += cnt[i]; }
    if (t == 255) row_ptr[NN] = run;
}

__global__ __launch_bounds__(256)
void fill_csr_k(const int* __restrict__ ei, const int* __restrict__ row_ptr,
                int* __restrict__ cursor, int* __restrict__ csr)
{
    int e = blockIdx.x * 256 + threadIdx.x;
    if (e >= EP) return;
    int s, d;
    if (e < EE) { s = ei[e]; d = ei[EE + e]; } else { s = e - EE; d = s; }
    int pos = row_ptr[d] + atomicAdd(&cursor[d], 1);
    csr[pos] = s;
}

// ---------------- hi/lo bf16 conversion of x + all weights (float4-vectorized) ----------------
#define C_X   2560000
#define C_EW  (C_X + 32768)
#define C_FW  (C_EW + 131072)      // gat_w (65536) + res_w (65536) -> fw rows 0..1023
#define C_DW  (C_FW + 5120)

__global__ __launch_bounds__(256)
void cvt_all_k(const float* __restrict__ x, const float* __restrict__ enc_w,
               const float* __restrict__ gat_w, const float* __restrict__ res_w,
               const float* __restrict__ dec_w,
               unsigned short* __restrict__ xhi, unsigned short* __restrict__ xlo,
               unsigned short* __restrict__ ewhi, unsigned short* __restrict__ ewlo,
               unsigned short* __restrict__ fwhi, unsigned short* __restrict__ fwlo,
               unsigned short* __restrict__ dwhi, unsigned short* __restrict__ dwlo)
{
    int i4 = blockIdx.x * 256 + threadIdx.x;
    int i = i4 * 4;
    if (i >= C_DW) return;
    const float* src = nullptr; unsigned short *ph, *pl; int j;
    if (i < C_X)       { j = i;        src = x;     ph = xhi;  pl = xlo; }
    else if (i < C_EW) { j = i - C_X;  src = enc_w; ph = ewhi; pl = ewlo; }
    else if (i < C_FW) { j = i - C_EW; ph = fwhi;   pl = fwlo; }
    else               { j = i - C_FW; src = dec_w; ph = dwhi; pl = dwlo; }

    float4 v;
    if (src) v = *(const float4*)(src + j);
    else     v = (j < 65536) ? *(const float4*)(gat_w + j) : *(const float4*)(res_w + j - 65536);
    float vv[4] = {v.x, v.y, v.z, v.w};
    unsigned short hs[4], ls[4];
#pragma unroll
    for (int k = 0; k < 4; ++k) {
        hs[k] = f2bf(vv[k]);
        ls[k] = f2bf(vv[k] - bf2f(hs[k]));
    }
    *(ushort4*)(ph + j) = make_ushort4(hs[0], hs[1], hs[2], hs[3]);
    *(ushort4*)(pl + j) = make_ushort4(ls[0], ls[1], ls[2], ls[3]);
}

// ---------------- fused attention weight rows: fw rows 1024..1031 (+ zero tail) ----------------
__global__ __launch_bounds__(256)
void attw_k(const float* __restrict__ gat_w, const float* __restrict__ att_src,
            const float* __restrict__ att_dst,
            unsigned short* __restrict__ fwhi, unsigned short* __restrict__ fwlo)
{
    int t = threadIdx.x;
#pragma unroll
    for (int i = 0; i < 4; ++i) {
        int idx = t + i * 256;          // 0..1023
        int is_dst = idx >= 512;
        int hk = is_dst ? idx - 512 : idx;
        int h = hk >> 7, k = hk & 127;
        const float* att = is_dst ? att_dst : att_src;
        float s = 0.0f;
        for (int c = 0; c < 128; ++c)
            s = fmaf(gat_w[(size_t)(h * 128 + c) * 128 + k], att[h * 128 + c], s);
        unsigned short hi = f2bf(s);
        size_t o = (size_t)(1024 + (is_dst ? 4 : 0) + h) * 128 + k;
        fwhi[o] = hi;
        fwlo[o] = f2bf(s - bf2f(hi));
    }
    for (int i = t; i < 56 * 128; i += 256) {
        fwhi[1032 * 128 + i] = 0;
        fwlo[1032 * 128 + i] = 0;
    }
}

// ---------------- bf16x3 MFMA GEMM: C = A @ W.T (+bias per mode) ----------------
// Block 64x64, 4 waves 2x2, wave 32x32 = 2x2 MFMA tiles. All fragments for up to
// 4 K-steps (32 x 16B loads, 128 VGPRs) are issued before MFMA consumes them ->
// deep memory pipeline (round-3 version had VGPR=44 and serialized loads: 5% MfmaUtil).
// acc += Ah*Wh + Ah*Wl + Al*Wh.
// MODE 0: dec  -> outF[row*40+col]+dec_b, cols masked < 40
// MODE 1: enc  -> relu(v+enc_b) -> hi/lo bf16 to outH/outL, ld=128
// MODE 2: layer-> col<512: bf16 xh; 512..1023: fp32 res (+res_b); 1024..1031: a_src/a_dst
template<int MODE, int KSTEPS>
__global__ __launch_bounds__(256, 2)
void gemm3_k(const unsigned short* __restrict__ Ahi, const unsigned short* __restrict__ Alo,
             const unsigned short* __restrict__ Bhi, const unsigned short* __restrict__ Blo,
             const float* __restrict__ bias,
             float* __restrict__ outF, unsigned short* __restrict__ outH,
             unsigned short* __restrict__ outL,
             float* __restrict__ a_src, float* __restrict__ a_dst, int M)
{
    constexpr int K = KSTEPS * 32;
    constexpr int PF = (KSTEPS < 4) ? KSTEPS : 4;   // prefetch depth (reg slots)
    const int lane = threadIdx.x & 63, wv = threadIdx.x >> 6;
    const int wr = (wv >> 1) * 32, wc = (wv & 1) * 32;
    const int bm = blockIdx.x * 64, bn = blockIdx.y * 64;
    const int r16 = lane & 15, q8 = (lane >> 4) * 8;

    const size_t a0 = (size_t)min(bm + wr + r16,      M - 1) * K + q8;
    const size_t a1 = (size_t)min(bm + wr + 16 + r16, M - 1) * K + q8;
    const size_t b0 = (size_t)(bn + wc + r16)      * K + q8;
    const size_t b1 = (size_t)(bn + wc + 16 + r16) * K + q8;

    bf8 fA0h[PF], fA1h[PF], fA0l[PF], fA1l[PF];
    bf8 fB0h[PF], fB1h[PF], fB0l[PF], fB1l[PF];

    f4 acc[2][2];
#pragma unroll
    for (int i = 0; i < 2; ++i)
#pragma unroll
        for (int j = 0; j < 2; ++j) acc[i][j] = (f4){0.f, 0.f, 0.f, 0.f};

#pragma unroll
    for (int ks = 0; ks < PF; ++ks) {
        const int ko = ks * 32;
        fA0h[ks] = *(const bf8*)(Ahi + a0 + ko);
        fA1h[ks] = *(const bf8*)(Ahi + a1 + ko);
        fA0l[ks] = *(const bf8*)(Alo + a0 + ko);
        fA1l[ks] = *(const bf8*)(Alo + a1 + ko);
        fB0h[ks] = *(const bf8*)(Bhi + b0 + ko);
        fB1h[ks] = *(const bf8*)(Bhi + b1 + ko);
        fB0l[ks] = *(const bf8*)(Blo + b0 + ko);
        fB1l[ks] = *(const bf8*)(Blo + b1 + ko);
    }

#pragma unroll
    for (int ks = 0; ks < KSTEPS; ++ks) {
        const int sl = ks % PF;
        bf8 A0h = fA0h[sl], A1h = fA1h[sl], A0l = fA0l[sl], A1l = fA1l[sl];
        bf8 B0h = fB0h[sl], B1h = fB1h[sl], B0l = fB0l[sl], B1l = fB1l[sl];
        if (ks + PF < KSTEPS) {           // refill slot for the rolling pipeline (K=256 case)
            const int ko = (ks + PF) * 32;
            fA0h[sl] = *(const bf8*)(Ahi + a0 + ko);
            fA1h[sl] = *(const bf8*)(Ahi + a1 + ko);
            fA0l[sl] = *(const bf8*)(Alo + a0 + ko);
            fA1l[sl] = *(const bf8*)(Alo + a1 + ko);
            fB0h[sl] = *(const bf8*)(Bhi + b0 + ko);
            fB1h[sl] = *(const bf8*)(Bhi + b1 + ko);
            fB0l[sl] = *(const bf8*)(Blo + b0 + ko);
            fB1l[sl] = *(const bf8*)(Blo + b1 + ko);
        }
        acc[0][0] = __builtin_amdgcn_mfma_f32_16x16x32_bf16(A0h, B0h, acc[0][0], 0, 0, 0);
        acc[0][1] = __builtin_amdgcn_mfma_f32_16x16x32_bf16(A0h, B1h, acc[0][1], 0, 0, 0);
        acc[1][0] = __builtin_amdgcn_mfma_f32_16x16x32_bf16(A1h, B0h, acc[1][0], 0, 0, 0);
        acc[1][1] = __builtin_amdgcn_mfma_f32_16x16x32_bf16(A1h, B1h, acc[1][1], 0, 0, 0);
        acc[0][0] = __builtin_amdgcn_mfma_f32_16x16x32_bf16(A0h, B0l, acc[0][0], 0, 0, 0);
        acc[0][1] = __builtin_amdgcn_mfma_f32_16x16x32_bf16(A0h, B1l, acc[0][1], 0, 0, 0);
        acc[1][0] = __builtin_amdgcn_mfma_f32_16x16x32_bf16(A1h, B0l, acc[1][0], 0, 0, 0);
        acc[1][1] = __builtin_amdgcn_mfma_f32_16x16x32_bf16(A1h, B1l, acc[1][1], 0, 0, 0);
        acc[0][0] = __builtin_amdgcn_mfma_f32_16x16x32_bf16(A0l, B0h, acc[0][0], 0, 0, 0);
        acc[0][1] = __builtin_amdgcn_mfma_f32_16x16x32_bf16(A0l, B1h, acc[0][1], 0, 0, 0);
        acc[1][0] = __builtin_amdgcn_mfma_f32_16x16x32_bf16(A1l, B0h, acc[1][0], 0, 0, 0);
        acc[1][1] = __builtin_amdgcn_mfma_f32_16x16x32_bf16(A1l, B1h, acc[1][1], 0, 0, 0);
    }

    const int rbase = (lane >> 4) * 4;
#pragma unroll
    for (int i = 0; i < 2; ++i)
#pragma unroll
        for (int j = 0; j < 2; ++j)
#pragma unroll
            for (int r = 0; r < 4; ++r) {
                int row = bm + wr + i * 16 + rbase + r;
                int col = bn + wc + j * 16 + r16;
                if (row >= M) continue;
                float v = acc[i][j][r];
                if (MODE == 1) {
                    v = fmaxf(v + bias[col], 0.0f);
                    unsigned short h = f2bf(v);
                    outH[(size_t)row * 128 + col] = h;
                    outL[(size_t)row * 128 + col] = f2bf(v - bf2f(h));
                } else if (MODE == 2) {
                    if (col < 512) {
                        outH[(size_t)row * 512 + col] = f2bf(v);
                    } else if (col < 1024) {
                        outF[(size_t)row * 512 + col - 512] = v + bias[col - 512];
                    } else if (col < 1032) {
                        int h = col - 1024;
                        if (h < 4) a_src[row * 4 + h] = v;
                        else       a_dst[row * 4 + h - 4] = v;
                    }
                } else {
                    if (col < NCLASS)
                        outF[(size_t)row * NCLASS + col] = v + bias[col];
                }
            }
}

// ---------------- per-edge unnormalized softmax weights (head-major) + per-node sums ------
__global__ __launch_bounds__(256)
void alpha_k(const int* __restrict__ row_ptr, const int* __restrict__ csr,
             const float* __restrict__ a_src, const float* __restrict__ a_dst,
             float* __restrict__ t, float* __restrict__ ssum)
{
    int wave = threadIdx.x >> 6, lane = threadIdx.x & 63;
    int d = blockIdx.x * 4 + wave;
    if (d >= NN) return;
    int beg = row_ptr[d], end = row_ptr[d + 1];
    float4 ad = *(const float4*)(a_dst + d * 4);
    float s0 = 0.f, s1 = 0.f, s2 = 0.f, s3 = 0.f;
    for (int e = beg + lane; e < end; e += 64) {
        int s = csr[e];
        float4 as = *(const float4*)(a_src + s * 4);
        float t0 = expf(leaky02(as.x + ad.x));
        float t1 = expf(leaky02(as.y + ad.y));
        float t2 = expf(leaky02(as.z + ad.z));
        float t3 = expf(leaky02(as.w + ad.w));
        t[0 * EP + e] = t0;
        t[1 * EP + e] = t1;
        t[2 * EP + e] = t2;
        t[3 * EP + e] = t3;
        s0 += t0; s1 += t1; s2 += t2; s3 += t3;
    }
#pragma unroll
    for (int off = 32; off >= 1; off >>= 1) {
        s0 += __shfl_xor(s0, off);
        s1 += __shfl_xor(s1, off);
        s2 += __shfl_xor(s2, off);
        s3 += __shfl_xor(s3, off);
    }
    if (lane == 0) *(float4*)(ssum + d * 4) = make_float4(s0, s1, s2, s3);
}

// ---------------- gather + residual + ELU + head-mean -> X (hi/lo bf16) ----------------
__global__ __launch_bounds__(256)
void agg_k(const int* __restrict__ row_ptr, const int* __restrict__ csr,
           const float* __restrict__ t, const float* __restrict__ ssum,
           const unsigned short* __restrict__ xh_b, const float* __restrict__ res,
           const float* __restrict__ gat_b,
           unsigned short* __restrict__ Xhi, unsigned short* __restrict__ Xlo)
{
    int wave = threadIdx.x >> 6, lane = threadIdx.x & 63;
    int d = blockIdx.x * 4 + wave;
    if (d >= NN) return;
    int beg = row_ptr[d], end = row_ptr[d + 1];
    int hl = lane >> 4;                       // head owned by this lane's cols
    int cb = lane * 8;                        // 8 bf16 cols = 16 B per lane
    const float* th = t + (size_t)hl * EP;

    float acc[8];
#pragma unroll
    for (int k = 0; k < 8; ++k) acc[k] = 0.0f;

    int e = beg;
    for (; e + 4 <= end; e += 4) {
        int s0v = csr[e + 0], s1v = csr[e + 1], s2v = csr[e + 2], s3v = csr[e + 3];
        float w0 = th[e + 0], w1 = th[e + 1], w2 = th[e + 2], w3 = th[e + 3];
        u16x8 v0 = *(const u16x8*)(xh_b + (size_t)s0v * HF + cb);
        u16x8 v1 = *(const u16x8*)(xh_b + (size_t)s1v * HF + cb);
        u16x8 v2 = *(const u16x8*)(xh_b + (size_t)s2v * HF + cb);
        u16x8 v3 = *(const u16x8*)(xh_b + (size_t)s3v * HF + cb);
#pragma unroll
        for (int k = 0; k < 8; ++k) acc[k] = fmaf(w0, bf2f(v0[k]), acc[k]);
#pragma unroll
        for (int k = 0; k < 8; ++k) acc[k] = fmaf(w1, bf2f(v1[k]), acc[k]);
#pragma unroll
        for (int k = 0; k < 8; ++k) acc[k] = fmaf(w2, bf2f(v2[k]), acc[k]);
#pragma unroll
        for (int k = 0; k < 8; ++k) acc[k] = fmaf(w3, bf2f(v3[k]), acc[k]);
    }
    for (; e < end; ++e) {
        int s = csr[e];
        float w = th[e];
        u16x8 v = *(const u16x8*)(xh_b + (size_t)s * HF + cb);
#pragma unroll
        for (int k = 0; k < 8; ++k) acc[k] = fmaf(w, bf2f(v[k]), acc[k]);
    }

    float inv = 1.0f / ssum[d * 4 + hl];
    const float* rr = res + (size_t)d * HF + cb;
    const float* gb = gat_b + cb;
    float u[8];
#pragma unroll
    for (int k = 0; k < 8; ++k) {
        float v = fmaf(acc[k], inv, gb[k] + rr[k]);
        u[k] = (v > 0.0f) ? v : expm1f(v);
    }
    float z0 = (u[0] + u[1] + u[2] + u[3]) * 0.25f;
    float z1 = (u[4] + u[5] + u[6] + u[7]) * 0.25f;
    unsigned short h0 = f2bf(z0), h1 = f2bf(z1);
    unsigned short l0 = f2bf(z0 - bf2f(h0)), l1 = f2bf(z1 - bf2f(h1));
    size_t idx = (size_t)d * NHID + lane * 2;
    *(unsigned*)(Xhi + idx) = ((unsigned)h1 << 16) | h0;
    *(unsigned*)(Xlo + idx) = ((unsigned)l1 << 16) | l0;
}

// ---------------- launcher ----------------
extern "C" void kernel_launch(void* const* d_in, const int* in_sizes, int n_in,
                              void* d_out, int out_size, void* d_ws, size_t ws_size,
                              hipStream_t stream)
{
    const float* x       = (const float*)d_in[0];
    const int*   ei      = (const int*)d_in[1];
    const float* enc_w   = (const float*)d_in[2];
    const float* enc_b   = (const float*)d_in[3];
    const float* res_w   = (const float*)d_in[4];
    const float* res_b   = (const float*)d_in[5];
    const float* gat_w   = (const float*)d_in[6];
    const float* att_src = (const float*)d_in[7];
    const float* att_dst = (const float*)d_in[8];
    const float* gat_b   = (const float*)d_in[9];
    const float* dec_w   = (const float*)d_in[10];
    const float* dec_b   = (const float*)d_in[11];
    float* out = (float*)d_out;

    char* p = (char*)d_ws;
    auto alloc = [&](size_t bytes) -> void* {
        void* r = (void*)p;
        p += (bytes + 255) & ~(size_t)255;
        return r;
    };
    float* res    = (float*)alloc(5120000 * 4);            // [N,512] fp32
    float* t      = (float*)alloc(4 * EP * 4);             // [4][EP] head-major
    float* a_src  = (float*)alloc(40000 * 4);
    float* a_dst  = (float*)alloc(40000 * 4);
    float* ssum   = (float*)alloc(40000 * 4);
    unsigned short* xh_b = (unsigned short*)alloc(5120000 * 2);     // [N,512] bf16
    unsigned short* Xhi  = (unsigned short*)alloc(1280000 * 2);     // [N,128] bf16
    unsigned short* Xlo  = (unsigned short*)alloc(1280000 * 2);
    unsigned short* xhi  = (unsigned short*)alloc(2560000 * 2);     // x hi/lo [N,256]
    unsigned short* xlo  = (unsigned short*)alloc(2560000 * 2);
    unsigned short* ewhi = (unsigned short*)alloc(32768 * 2);       // enc_w [128,256]
    unsigned short* ewlo = (unsigned short*)alloc(32768 * 2);
    unsigned short* fwhi = (unsigned short*)alloc(FCOLS * 128 * 2); // [1088,128]
    unsigned short* fwlo = (unsigned short*)alloc(FCOLS * 128 * 2);
    int* row_ptr = (int*)alloc(10004 * 4);
    int* csr     = (int*)alloc(170000 * 4);
    // ---- zero zone (single memset): padded dec W + cnt + cursor ----
    char* zbase = p;
    unsigned short* dwhi = (unsigned short*)alloc(8192 * 2);        // [64,128] padded
    unsigned short* dwlo = (unsigned short*)alloc(8192 * 2);
    int* cnt    = (int*)alloc(10000 * 4);
    int* cursor = (int*)alloc(10000 * 4);
    size_t zbytes = (size_t)(p - zbase);

    hipMemsetAsync(zbase, 0, zbytes, stream);

    // CSR build (graph static across both layers)
    int eb = (EP + 255) / 256;
    count_edges_k<<<eb, 256, 0, stream>>>(ei, cnt);
    scan_k<<<1, 256, 0, stream>>>(cnt, row_ptr);
    fill_csr_k<<<eb, 256, 0, stream>>>(ei, row_ptr, cursor, csr);

    // hi/lo conversions (x + all weights), float4-vectorized
    cvt_all_k<<<(C_DW / 4 + 255) / 256, 256, 0, stream>>>(
        x, enc_w, gat_w, res_w, dec_w,
        xhi, xlo, ewhi, ewlo, fwhi, fwlo, dwhi, dwlo);
    // fused attention weight rows (fw rows 1024..1031 + zero tail)
    attw_k<<<1, 256, 0, stream>>>(gat_w, att_src, att_dst, fwhi, fwlo);

    // encoder: X = relu(x @ enc_w.T + enc_b) -> hi/lo bf16
    gemm3_k<1, 8><<<dim3(157, 2), 256, 0, stream>>>(
        xhi, xlo, ewhi, ewlo, enc_b, nullptr, Xhi, Xlo, nullptr, nullptr, NN);

    for (int layer = 0; layer < 2; ++layer) {
        // fused [xh | res | a_src a_dst] = X @ [gat_w; res_w; As; Ad].T
        gemm3_k<2, 4><<<dim3(157, 17), 256, 0, stream>>>(
            Xhi, Xlo, fwhi, fwlo, res_b, res, xh_b, nullptr, a_src, a_dst, NN);
        alpha_k<<<2500, 256, 0, stream>>>(row_ptr, csr, a_src, a_dst, t, ssum);
        agg_k<<<2500, 256, 0, stream>>>(row_ptr, csr, t, ssum, xh_b, res, gat_b, Xhi, Xlo);
    }

    // decoder: out = X @ dec_w.T + dec_b
    gemm3_k<0, 4><<<dim3(157, 1), 256, 0, stream>>>(
        Xhi, Xlo, dwhi, dwlo, dec_b, out, nullptr, nullptr, nullptr, nullptr, NN);
}

// Round 5
// 294.624 us; speedup vs baseline: 1.1960x; 1.1960x over previous
//
#include <hip/hip_runtime.h>
#include <math.h>

#define NN 10000
#define EE 160000
#define EP 170000          // EE + NN self loops
#define NFEAT 256
#define NHID 128
#define NH 4
#define HF 512             // NH * NHID
#define NCLASS 40
#define FCOLS 1088         // 512 xh + 512 res + 8 attn + 56 pad

typedef __attribute__((ext_vector_type(8))) short bf8;     // 8 bf16 (4 VGPR) MFMA frag
typedef __attribute__((ext_vector_type(8))) unsigned short u16x8;
typedef __attribute__((ext_vector_type(4))) float f4;

__device__ __forceinline__ float leaky02(float x) { return x >= 0.0f ? x : 0.2f * x; }

__device__ __forceinline__ unsigned short f2bf(float f) {   // RNE
    unsigned u = __builtin_bit_cast(unsigned, f);
    unsigned r = (u + 0x7FFF + ((u >> 16) & 1)) >> 16;
    return (unsigned short)r;
}
__device__ __forceinline__ float bf2f(unsigned short h) {
    return __builtin_bit_cast(float, (unsigned)h << 16);
}

// ---------------- CSR build ----------------
__global__ __launch_bounds__(256)
void count_edges_k(const int* __restrict__ ei, int* __restrict__ cnt)
{
    int e = blockIdx.x * 256 + threadIdx.x;
    if (e >= EP) return;
    int d = (e < EE) ? ei[EE + e] : (e - EE);
    atomicAdd(&cnt[d], 1);
}

__global__ __launch_bounds__(256)
void scan_k(const int* __restrict__ cnt, int* __restrict__ row_ptr)
{
    __shared__ int sm[256];
    int t = threadIdx.x;
    int i0 = t * 40, i1 = min(i0 + 40, NN);
    int part = 0;
    for (int i = i0; i < i1; ++i) part += cnt[i];
    sm[t] = part;
    __syncthreads();
    for (int off = 1; off < 256; off <<= 1) {
        int v = (t >= off) ? sm[t - off] : 0;
        __syncthreads();
        sm[t] += v;
        __syncthreads();
    }
    int run = sm[t] - part;             // exclusive prefix
    for (int i = i0; i < i1; ++i) { row_ptr[i] = run; run += cnt[i]; }
    if (t == 255) row_ptr[NN] = run;
}

__global__ __launch_bounds__(256)
void fill_csr_k(const int* __restrict__ ei, const int* __restrict__ row_ptr,
                int* __restrict__ cursor, int* __restrict__ csr)
{
    int e = blockIdx.x * 256 + threadIdx.x;
    if (e >= EP) return;
    int s, d;
    if (e < EE) { s = ei[e]; d = ei[EE + e]; } else { s = e - EE; d = s; }
    int pos = row_ptr[d] + atomicAdd(&cursor[d], 1);
    csr[pos] = s;
}

// ---------------- hi/lo bf16 conversion of x + all weights (float4-vectorized) ----------------
#define C_X   2560000
#define C_EW  (C_X + 32768)
#define C_FW  (C_EW + 131072)      // gat_w (65536) + res_w (65536) -> fw rows 0..1023
#define C_DW  (C_FW + 5120)

__global__ __launch_bounds__(256)
void cvt_all_k(const float* __restrict__ x, const float* __restrict__ enc_w,
               const float* __restrict__ gat_w, const float* __restrict__ res_w,
               const float* __restrict__ dec_w,
               unsigned short* __restrict__ xhi, unsigned short* __restrict__ xlo,
               unsigned short* __restrict__ ewhi, unsigned short* __restrict__ ewlo,
               unsigned short* __restrict__ fwhi, unsigned short* __restrict__ fwlo,
               unsigned short* __restrict__ dwhi, unsigned short* __restrict__ dwlo)
{
    int i4 = blockIdx.x * 256 + threadIdx.x;
    int i = i4 * 4;
    if (i >= C_DW) return;
    const float* src = nullptr; unsigned short *ph, *pl; int j;
    if (i < C_X)       { j = i;        src = x;     ph = xhi;  pl = xlo; }
    else if (i < C_EW) { j = i - C_X;  src = enc_w; ph = ewhi; pl = ewlo; }
    else if (i < C_FW) { j = i - C_EW; ph = fwhi;   pl = fwlo; }
    else               { j = i - C_FW; src = dec_w; ph = dwhi; pl = dwlo; }

    float4 v;
    if (src) v = *(const float4*)(src + j);
    else     v = (j < 65536) ? *(const float4*)(gat_w + j) : *(const float4*)(res_w + j - 65536);
    float vv[4] = {v.x, v.y, v.z, v.w};
    unsigned short hs[4], ls[4];
#pragma unroll
    for (int k = 0; k < 4; ++k) {
        hs[k] = f2bf(vv[k]);
        ls[k] = f2bf(vv[k] - bf2f(hs[k]));
    }
    *(ushort4*)(ph + j) = make_ushort4(hs[0], hs[1], hs[2], hs[3]);
    *(ushort4*)(pl + j) = make_ushort4(ls[0], ls[1], ls[2], ls[3]);
}

// ---------------- fused attention weight rows: fw rows 1024..1031 (+ zero tail) ----------------
__global__ __launch_bounds__(256)
void attw_k(const float* __restrict__ gat_w, const float* __restrict__ att_src,
            const float* __restrict__ att_dst,
            unsigned short* __restrict__ fwhi, unsigned short* __restrict__ fwlo)
{
    int t = threadIdx.x;
#pragma unroll
    for (int i = 0; i < 4; ++i) {
        int idx = t + i * 256;          // 0..1023
        int is_dst = idx >= 512;
        int hk = is_dst ? idx - 512 : idx;
        int h = hk >> 7, k = hk & 127;
        const float* att = is_dst ? att_dst : att_src;
        float s = 0.0f;
        for (int c = 0; c < 128; ++c)
            s = fmaf(gat_w[(size_t)(h * 128 + c) * 128 + k], att[h * 128 + c], s);
        unsigned short hi = f2bf(s);
        size_t o = (size_t)(1024 + (is_dst ? 4 : 0) + h) * 128 + k;
        fwhi[o] = hi;
        fwlo[o] = f2bf(s - bf2f(hi));
    }
    for (int i = t; i < 56 * 128; i += 256) {
        fwhi[1032 * 128 + i] = 0;
        fwlo[1032 * 128 + i] = 0;
    }
}

// ---------------- bf16x3 MFMA GEMM via LDS staging ----------------
// Block 64x64, 4 waves 2x2, wave 32x32 = 2x2 MFMA tiles. Whole block tile (A hi/lo,
// B hi/lo, 64x128 bf16 each = 64 KB) staged to LDS with coalesced 16B copies, then
// the K-loop is pure ds_read_b128 + MFMA (compiler pipelines lgkmcnt near-optimally).
// 16B-unit XOR swizzle (u ^= row&7) keeps LDS bank aliasing at ~2-way (free).
// Round-3/4 registers-only gather was latency-bound: compiler sank loads (VGPR=44,
// MfmaUtil 5%). acc += Ah*Wh + Ah*Wl + Al*Wh.
// MODE 0: dec  -> outF[row*40+col]+dec_b, cols masked < 40
// MODE 1: enc  -> relu(v+enc_b) -> hi/lo bf16 to outH/outL, ld=128
// MODE 2: layer-> col<512: bf16 xh; 512..1023: fp32 res (+res_b); 1024..1031: a_src/a_dst
template<int MODE, int KTILES>
__global__ __launch_bounds__(256)
void gemm3_k(const unsigned short* __restrict__ Ahi, const unsigned short* __restrict__ Alo,
             const unsigned short* __restrict__ Bhi, const unsigned short* __restrict__ Blo,
             const float* __restrict__ bias,
             float* __restrict__ outF, unsigned short* __restrict__ outH,
             unsigned short* __restrict__ outL,
             float* __restrict__ a_src, float* __restrict__ a_dst, int M)
{
    constexpr int K = KTILES * 128;
    __shared__ unsigned short sAh[64 * 128];
    __shared__ unsigned short sAl[64 * 128];
    __shared__ unsigned short sBh[64 * 128];
    __shared__ unsigned short sBl[64 * 128];

    const int tid = threadIdx.x;
    const int lane = tid & 63, wv = tid >> 6;
    const int wr = (wv >> 1) * 32, wc = (wv & 1) * 32;
    const int bm = blockIdx.x * 64, bn = blockIdx.y * 64;
    const int r16 = lane & 15, q4 = lane >> 4;

    f4 acc[2][2];
#pragma unroll
    for (int i = 0; i < 2; ++i)
#pragma unroll
        for (int j = 0; j < 2; ++j) acc[i][j] = (f4){0.f, 0.f, 0.f, 0.f};

    // fragment LDS offsets (elements); swizzle class of row r is r&7
    const int ra0 = wr + r16, ra1 = ra0 + 16;        // (ra0&7)==(ra1&7)
    const int rb0 = wc + r16, rb1 = rb0 + 16;

    for (int kt = 0; kt < KTILES; ++kt) {
        if (kt) __syncthreads();
        // ---- stage: 1024 16B-units per tensor, 4 per thread per tensor ----
#pragma unroll
        for (int j = 0; j < 4; ++j) {
            int i = tid + j * 256;                    // unit index 0..1023
            int row = i >> 4, u = i & 15;
            int arow = min(bm + row, M - 1);
            int brow = bn + row;
            size_t ga = (size_t)arow * K + kt * 128 + u * 8;
            size_t gb = (size_t)brow * K + kt * 128 + u * 8;
            int lo = row * 128 + ((u ^ (row & 7)) * 8);
            *(u16x8*)(sAh + lo) = *(const u16x8*)(Ahi + ga);
            *(u16x8*)(sAl + lo) = *(const u16x8*)(Alo + ga);
            *(u16x8*)(sBh + lo) = *(const u16x8*)(Bhi + gb);
            *(u16x8*)(sBl + lo) = *(const u16x8*)(Blo + gb);
        }
        __syncthreads();

        // ---- compute: 4 K-steps of 32, 8 ds_read_b128 + 12 MFMA each ----
#pragma unroll
        for (int ks = 0; ks < 4; ++ks) {
            int u = ks * 4 + q4;
            int oa0 = ra0 * 128 + ((u ^ (ra0 & 7)) * 8);
            int ob0 = rb0 * 128 + ((u ^ (rb0 & 7)) * 8);
            int oa1 = oa0 + 16 * 128;
            int ob1 = ob0 + 16 * 128;
            bf8 A0h = *(const bf8*)(sAh + oa0);
            bf8 A1h = *(const bf8*)(sAh + oa1);
            bf8 A0l = *(const bf8*)(sAl + oa0);
            bf8 A1l = *(const bf8*)(sAl + oa1);
            bf8 B0h = *(const bf8*)(sBh + ob0);
            bf8 B1h = *(const bf8*)(sBh + ob1);
            bf8 B0l = *(const bf8*)(sBl + ob0);
            bf8 B1l = *(const bf8*)(sBl + ob1);

            acc[0][0] = __builtin_amdgcn_mfma_f32_16x16x32_bf16(A0h, B0h, acc[0][0], 0, 0, 0);
            acc[0][1] = __builtin_amdgcn_mfma_f32_16x16x32_bf16(A0h, B1h, acc[0][1], 0, 0, 0);
            acc[1][0] = __builtin_amdgcn_mfma_f32_16x16x32_bf16(A1h, B0h, acc[1][0], 0, 0, 0);
            acc[1][1] = __builtin_amdgcn_mfma_f32_16x16x32_bf16(A1h, B1h, acc[1][1], 0, 0, 0);
            acc[0][0] = __builtin_amdgcn_mfma_f32_16x16x32_bf16(A0h, B0l, acc[0][0], 0, 0, 0);
            acc[0][1] = __builtin_amdgcn_mfma_f32_16x16x32_bf16(A0h, B1l, acc[0][1], 0, 0, 0);
            acc[1][0] = __builtin_amdgcn_mfma_f32_16x16x32_bf16(A1h, B0l, acc[1][0], 0, 0, 0);
            acc[1][1] = __builtin_amdgcn_mfma_f32_16x16x32_bf16(A1h, B1l, acc[1][1], 0, 0, 0);
            acc[0][0] = __builtin_amdgcn_mfma_f32_16x16x32_bf16(A0l, B0h, acc[0][0], 0, 0, 0);
            acc[0][1] = __builtin_amdgcn_mfma_f32_16x16x32_bf16(A0l, B1h, acc[0][1], 0, 0, 0);
            acc[1][0] = __builtin_amdgcn_mfma_f32_16x16x32_bf16(A1l, B0h, acc[1][0], 0, 0, 0);
            acc[1][1] = __builtin_amdgcn_mfma_f32_16x16x32_bf16(A1l, B1h, acc[1][1], 0, 0, 0);
        }
    }

    const int rbase = q4 * 4;
#pragma unroll
    for (int i = 0; i < 2; ++i)
#pragma unroll
        for (int j = 0; j < 2; ++j)
#pragma unroll
            for (int r = 0; r < 4; ++r) {
                int row = bm + wr + i * 16 + rbase + r;
                int col = bn + wc + j * 16 + r16;
                if (row >= M) continue;
                float v = acc[i][j][r];
                if (MODE == 1) {
                    v = fmaxf(v + bias[col], 0.0f);
                    unsigned short h = f2bf(v);
                    outH[(size_t)row * 128 + col] = h;
                    outL[(size_t)row * 128 + col] = f2bf(v - bf2f(h));
                } else if (MODE == 2) {
                    if (col < 512) {
                        outH[(size_t)row * 512 + col] = f2bf(v);
                    } else if (col < 1024) {
                        outF[(size_t)row * 512 + col - 512] = v + bias[col - 512];
                    } else if (col < 1032) {
                        int h = col - 1024;
                        if (h < 4) a_src[row * 4 + h] = v;
                        else       a_dst[row * 4 + h - 4] = v;
                    }
                } else {
                    if (col < NCLASS)
                        outF[(size_t)row * NCLASS + col] = v + bias[col];
                }
            }
}

// ---------------- per-edge unnormalized softmax weights (head-major) + per-node sums ------
__global__ __launch_bounds__(256)
void alpha_k(const int* __restrict__ row_ptr, const int* __restrict__ csr,
             const float* __restrict__ a_src, const float* __restrict__ a_dst,
             float* __restrict__ t, float* __restrict__ ssum)
{
    int wave = threadIdx.x >> 6, lane = threadIdx.x & 63;
    int d = blockIdx.x * 4 + wave;
    if (d >= NN) return;
    int beg = row_ptr[d], end = row_ptr[d + 1];
    float4 ad = *(const float4*)(a_dst + d * 4);
    float s0 = 0.f, s1 = 0.f, s2 = 0.f, s3 = 0.f;
    for (int e = beg + lane; e < end; e += 64) {
        int s = csr[e];
        float4 as = *(const float4*)(a_src + s * 4);
        float t0 = expf(leaky02(as.x + ad.x));
        float t1 = expf(leaky02(as.y + ad.y));
        float t2 = expf(leaky02(as.z + ad.z));
        float t3 = expf(leaky02(as.w + ad.w));
        t[0 * EP + e] = t0;
        t[1 * EP + e] = t1;
        t[2 * EP + e] = t2;
        t[3 * EP + e] = t3;
        s0 += t0; s1 += t1; s2 += t2; s3 += t3;
    }
#pragma unroll
    for (int off = 32; off >= 1; off >>= 1) {
        s0 += __shfl_xor(s0, off);
        s1 += __shfl_xor(s1, off);
        s2 += __shfl_xor(s2, off);
        s3 += __shfl_xor(s3, off);
    }
    if (lane == 0) *(float4*)(ssum + d * 4) = make_float4(s0, s1, s2, s3);
}

// ---------------- gather + residual + ELU + head-mean -> X (hi/lo bf16) ----------------
__global__ __launch_bounds__(256)
void agg_k(const int* __restrict__ row_ptr, const int* __restrict__ csr,
           const float* __restrict__ t, const float* __restrict__ ssum,
           const unsigned short* __restrict__ xh_b, const float* __restrict__ res,
           const float* __restrict__ gat_b,
           unsigned short* __restrict__ Xhi, unsigned short* __restrict__ Xlo)
{
    int wave = threadIdx.x >> 6, lane = threadIdx.x & 63;
    int d = blockIdx.x * 4 + wave;
    if (d >= NN) return;
    int beg = row_ptr[d], end = row_ptr[d + 1];
    int hl = lane >> 4;                       // head owned by this lane's cols
    int cb = lane * 8;                        // 8 bf16 cols = 16 B per lane
    const float* th = t + (size_t)hl * EP;

    float acc[8];
#pragma unroll
    for (int k = 0; k < 8; ++k) acc[k] = 0.0f;

    int e = beg;
    for (; e + 4 <= end; e += 4) {
        int s0v = csr[e + 0], s1v = csr[e + 1], s2v = csr[e + 2], s3v = csr[e + 3];
        float w0 = th[e + 0], w1 = th[e + 1], w2 = th[e + 2], w3 = th[e + 3];
        u16x8 v0 = *(const u16x8*)(xh_b + (size_t)s0v * HF + cb);
        u16x8 v1 = *(const u16x8*)(xh_b + (size_t)s1v * HF + cb);
        u16x8 v2 = *(const u16x8*)(xh_b + (size_t)s2v * HF + cb);
        u16x8 v3 = *(const u16x8*)(xh_b + (size_t)s3v * HF + cb);
#pragma unroll
        for (int k = 0; k < 8; ++k) acc[k] = fmaf(w0, bf2f(v0[k]), acc[k]);
#pragma unroll
        for (int k = 0; k < 8; ++k) acc[k] = fmaf(w1, bf2f(v1[k]), acc[k]);
#pragma unroll
        for (int k = 0; k < 8; ++k) acc[k] = fmaf(w2, bf2f(v2[k]), acc[k]);
#pragma unroll
        for (int k = 0; k < 8; ++k) acc[k] = fmaf(w3, bf2f(v3[k]), acc[k]);
    }
    for (; e < end; ++e) {
        int s = csr[e];
        float w = th[e];
        u16x8 v = *(const u16x8*)(xh_b + (size_t)s * HF + cb);
#pragma unroll
        for (int k = 0; k < 8; ++k) acc[k] = fmaf(w, bf2f(v[k]), acc[k]);
    }

    float inv = 1.0f / ssum[d * 4 + hl];
    const float* rr = res + (size_t)d * HF + cb;
    const float* gb = gat_b + cb;
    float u[8];
#pragma unroll
    for (int k = 0; k < 8; ++k) {
        float v = fmaf(acc[k], inv, gb[k] + rr[k]);
        u[k] = (v > 0.0f) ? v : expm1f(v);
    }
    float z0 = (u[0] + u[1] + u[2] + u[3]) * 0.25f;
    float z1 = (u[4] + u[5] + u[6] + u[7]) * 0.25f;
    unsigned short h0 = f2bf(z0), h1 = f2bf(z1);
    unsigned short l0 = f2bf(z0 - bf2f(h0)), l1 = f2bf(z1 - bf2f(h1));
    size_t idx = (size_t)d * NHID + lane * 2;
    *(unsigned*)(Xhi + idx) = ((unsigned)h1 << 16) | h0;
    *(unsigned*)(Xlo + idx) = ((unsigned)l1 << 16) | l0;
}

// ---------------- launcher ----------------
extern "C" void kernel_launch(void* const* d_in, const int* in_sizes, int n_in,
                              void* d_out, int out_size, void* d_ws, size_t ws_size,
                              hipStream_t stream)
{
    const float* x       = (const float*)d_in[0];
    const int*   ei      = (const int*)d_in[1];
    const float* enc_w   = (const float*)d_in[2];
    const float* enc_b   = (const float*)d_in[3];
    const float* res_w   = (const float*)d_in[4];
    const float* res_b   = (const float*)d_in[5];
    const float* gat_w   = (const float*)d_in[6];
    const float* att_src = (const float*)d_in[7];
    const float* att_dst = (const float*)d_in[8];
    const float* gat_b   = (const float*)d_in[9];
    const float* dec_w   = (const float*)d_in[10];
    const float* dec_b   = (const float*)d_in[11];
    float* out = (float*)d_out;

    char* p = (char*)d_ws;
    auto alloc = [&](size_t bytes) -> void* {
        void* r = (void*)p;
        p += (bytes + 255) & ~(size_t)255;
        return r;
    };
    float* res    = (float*)alloc(5120000 * 4);            // [N,512] fp32
    float* t      = (float*)alloc(4 * EP * 4);             // [4][EP] head-major
    float* a_src  = (float*)alloc(40000 * 4);
    float* a_dst  = (float*)alloc(40000 * 4);
    float* ssum   = (float*)alloc(40000 * 4);
    unsigned short* xh_b = (unsigned short*)alloc(5120000 * 2);     // [N,512] bf16
    unsigned short* Xhi  = (unsigned short*)alloc(1280000 * 2);     // [N,128] bf16
    unsigned short* Xlo  = (unsigned short*)alloc(1280000 * 2);
    unsigned short* xhi  = (unsigned short*)alloc(2560000 * 2);     // x hi/lo [N,256]
    unsigned short* xlo  = (unsigned short*)alloc(2560000 * 2);
    unsigned short* ewhi = (unsigned short*)alloc(32768 * 2);       // enc_w [128,256]
    unsigned short* ewlo = (unsigned short*)alloc(32768 * 2);
    unsigned short* fwhi = (unsigned short*)alloc(FCOLS * 128 * 2); // [1088,128]
    unsigned short* fwlo = (unsigned short*)alloc(FCOLS * 128 * 2);
    int* row_ptr = (int*)alloc(10004 * 4);
    int* csr     = (int*)alloc(170000 * 4);
    // ---- zero zone (single memset): padded dec W + cnt + cursor ----
    char* zbase = p;
    unsigned short* dwhi = (unsigned short*)alloc(8192 * 2);        // [64,128] padded
    unsigned short* dwlo = (unsigned short*)alloc(8192 * 2);
    int* cnt    = (int*)alloc(10000 * 4);
    int* cursor = (int*)alloc(10000 * 4);
    size_t zbytes = (size_t)(p - zbase);

    hipMemsetAsync(zbase, 0, zbytes, stream);

    // CSR build (graph static across both layers)
    int eb = (EP + 255) / 256;
    count_edges_k<<<eb, 256, 0, stream>>>(ei, cnt);
    scan_k<<<1, 256, 0, stream>>>(cnt, row_ptr);
    fill_csr_k<<<eb, 256, 0, stream>>>(ei, row_ptr, cursor, csr);

    // hi/lo conversions (x + all weights), float4-vectorized
    cvt_all_k<<<(C_DW / 4 + 255) / 256, 256, 0, stream>>>(
        x, enc_w, gat_w, res_w, dec_w,
        xhi, xlo, ewhi, ewlo, fwhi, fwlo, dwhi, dwlo);
    // fused attention weight rows (fw rows 1024..1031 + zero tail)
    attw_k<<<1, 256, 0, stream>>>(gat_w, att_src, att_dst, fwhi, fwlo);

    // encoder: X = relu(x @ enc_w.T + enc_b) -> hi/lo bf16  (K=256 -> 2 K-tiles)
    gemm3_k<1, 2><<<dim3(157, 2), 256, 0, stream>>>(
        xhi, xlo, ewhi, ewlo, enc_b, nullptr, Xhi, Xlo, nullptr, nullptr, NN);

    for (int layer = 0; layer < 2; ++layer) {
        // fused [xh | res | a_src a_dst] = X @ [gat_w; res_w; As; Ad].T
        gemm3_k<2, 1><<<dim3(157, 17), 256, 0, stream>>>(
            Xhi, Xlo, fwhi, fwlo, res_b, res, xh_b, nullptr, a_src, a_dst, NN);
        alpha_k<<<2500, 256, 0, stream>>>(row_ptr, csr, a_src, a_dst, t, ssum);
        agg_k<<<2500, 256, 0, stream>>>(row_ptr, csr, t, ssum, xh_b, res, gat_b, Xhi, Xlo);
    }

    // decoder: out = X @ dec_w.T + dec_b
    gemm3_k<0, 1><<<dim3(157, 1), 256, 0, stream>>>(
        Xhi, Xlo, dwhi, dwlo, dec_b, out, nullptr, nullptr, nullptr, nullptr, NN);
}

// Round 6
// 293.723 us; speedup vs baseline: 1.1997x; 1.0031x over previous
//
#include <hip/hip_runtime.h>
#include <math.h>

#define NN 10000
#define EE 160000
#define EP 170000          // EE + NN self loops
#define NFEAT 256
#define NHID 128
#define NH 4
#define HF 512             // NH * NHID
#define NCLASS 40
#define FCOLS 1088         // 512 xh + 512 res + 8 attn + 56 pad

typedef __attribute__((ext_vector_type(8))) short bf8;     // 8 bf16 (4 VGPR) MFMA frag
typedef __attribute__((ext_vector_type(8))) unsigned short u16x8;
typedef __attribute__((ext_vector_type(4))) float f4;

__device__ __forceinline__ float leaky02(float x) { return x >= 0.0f ? x : 0.2f * x; }

__device__ __forceinline__ unsigned short f2bf(float f) {   // RNE
    unsigned u = __builtin_bit_cast(unsigned, f);
    unsigned r = (u + 0x7FFF + ((u >> 16) & 1)) >> 16;
    return (unsigned short)r;
}
__device__ __forceinline__ float bf2f(unsigned short h) {
    return __builtin_bit_cast(float, (unsigned)h << 16);
}

// Bank-swizzled element position within a row of length K (baked into GLOBAL layout
// of all MFMA operands so that global->LDS staging is a LINEAR copy usable by
// global_load_lds). Unit u=c>>3 goes to physical unit u^(row&7) (permutes only
// within aligned groups of 8 units -> compatible with 128-col K-tiles).
__device__ __forceinline__ int swz(int row, int c) {
    return ((((c >> 3) ^ (row & 7)) << 3) | (c & 7));
}

// 16B global -> LDS direct DMA (lane l's 16B lands at ldsbase + l*16)
__device__ __forceinline__ void gl_lds16(const unsigned short* g, unsigned short* l)
{
    __builtin_amdgcn_global_load_lds(
        (const __attribute__((address_space(1))) unsigned int*)g,
        (__attribute__((address_space(3))) unsigned int*)l, 16, 0, 0);
}

// ---------------- CSR build ----------------
__global__ __launch_bounds__(256)
void count_edges_k(const int* __restrict__ ei, int* __restrict__ cnt)
{
    int e = blockIdx.x * 256 + threadIdx.x;
    if (e >= EP) return;
    int d = (e < EE) ? ei[EE + e] : (e - EE);
    atomicAdd(&cnt[d], 1);
}

__global__ __launch_bounds__(256)
void scan_k(const int* __restrict__ cnt, int* __restrict__ row_ptr)
{
    __shared__ int sm[256];
    int t = threadIdx.x;
    int i0 = t * 40, i1 = min(i0 + 40, NN);
    int part = 0;
    for (int i = i0; i < i1; ++i) part += cnt[i];
    sm[t] = part;
    __syncthreads();
    for (int off = 1; off < 256; off <<= 1) {
        int v = (t >= off) ? sm[t - off] : 0;
        __syncthreads();
        sm[t] += v;
        __syncthreads();
    }
    int run = sm[t] - part;             // exclusive prefix
    for (int i = i0; i < i1; ++i) { row_ptr[i] = run; run += cnt[i]; }
    if (t == 255) row_ptr[NN] = run;
}

__global__ __launch_bounds__(256)
void fill_csr_k(const int* __restrict__ ei, const int* __restrict__ row_ptr,
                int* __restrict__ cursor, int* __restrict__ csr)
{
    int e = blockIdx.x * 256 + threadIdx.x;
    if (e >= EP) return;
    int s, d;
    if (e < EE) { s = ei[e]; d = ei[EE + e]; } else { s = e - EE; d = s; }
    int pos = row_ptr[d] + atomicAdd(&cursor[d], 1);
    csr[pos] = s;
}

// ---------------- hi/lo bf16 conversion of x + all weights (swizzled layout) ----------------
#define C_X   2560000
#define C_EW  (C_X + 32768)
#define C_FW  (C_EW + 131072)      // gat_w (65536) + res_w (65536) -> fw rows 0..1023
#define C_DW  (C_FW + 5120)

__global__ __launch_bounds__(256)
void cvt_all_k(const float* __restrict__ x, const float* __restrict__ enc_w,
               const float* __restrict__ gat_w, const float* __restrict__ res_w,
               const float* __restrict__ dec_w,
               unsigned short* __restrict__ xhi, unsigned short* __restrict__ xlo,
               unsigned short* __restrict__ ewhi, unsigned short* __restrict__ ewlo,
               unsigned short* __restrict__ fwhi, unsigned short* __restrict__ fwlo,
               unsigned short* __restrict__ dwhi, unsigned short* __restrict__ dwlo)
{
    int iu = blockIdx.x * 256 + threadIdx.x;    // 8-element unit index
    int i = iu * 8;
    if (i >= C_DW) return;
    const float* src = nullptr; unsigned short *ph, *pl; int j, row, c;
    if (i < C_X)       { j = i;        src = x;     ph = xhi;  pl = xlo;
                         row = j >> 8; c = j & 255; }
    else if (i < C_EW) { j = i - C_X;  src = enc_w; ph = ewhi; pl = ewlo;
                         row = j >> 8; c = j & 255; }
    else if (i < C_FW) { j = i - C_EW; ph = fwhi;   pl = fwlo;
                         row = j >> 7; c = j & 127; }
    else               { j = i - C_FW; src = dec_w; ph = dwhi; pl = dwlo;
                         row = j >> 7; c = j & 127; }

    float4 v0, v1;
    if (src) { v0 = *(const float4*)(src + j); v1 = *(const float4*)(src + j + 4); }
    else {
        const float* s2 = (j < 65536) ? (gat_w + j) : (res_w + j - 65536);
        v0 = *(const float4*)s2; v1 = *(const float4*)(s2 + 4);
    }
    int o = (i - j) + row * ((c == (j & 255)) ? 0 : 0);  // (dummy to keep structure simple)
    (void)o;
    float vv[8] = {v0.x, v0.y, v0.z, v0.w, v1.x, v1.y, v1.z, v1.w};
    unsigned short hs[8], ls[8];
#pragma unroll
    for (int k = 0; k < 8; ++k) {
        hs[k] = f2bf(vv[k]);
        ls[k] = f2bf(vv[k] - bf2f(hs[k]));
    }
    int K = (c == (j & 255)) ? 0 : 0;   // unused
    (void)K;
    int Kd = (i < C_EW) ? 256 : 128;
    int out = row * Kd + swz(row, c);   // c multiple of 8 -> 8 contiguous elements
    *(u16x8*)(ph + out) = *(u16x8*)hs;
    *(u16x8*)(pl + out) = *(u16x8*)ls;
}

// ---------------- fused attention weight rows: fw rows 1024..1031 (+ zero tail) ----------------
__global__ __launch_bounds__(256)
void attw_k(const float* __restrict__ gat_w, const float* __restrict__ att_src,
            const float* __restrict__ att_dst,
            unsigned short* __restrict__ fwhi, unsigned short* __restrict__ fwlo)
{
    int t = threadIdx.x;
#pragma unroll
    for (int i = 0; i < 4; ++i) {
        int idx = t + i * 256;          // 0..1023
        int is_dst = idx >= 512;
        int hk = is_dst ? idx - 512 : idx;
        int h = hk >> 7, k = hk & 127;
        const float* att = is_dst ? att_dst : att_src;
        float s = 0.0f;
        for (int c = 0; c < 128; ++c)
            s = fmaf(gat_w[(size_t)(h * 128 + c) * 128 + k], att[h * 128 + c], s);
        unsigned short hi = f2bf(s);
        int R = 1024 + (is_dst ? 4 : 0) + h;
        size_t o = (size_t)R * 128 + swz(R, k);
        fwhi[o] = hi;
        fwlo[o] = f2bf(s - bf2f(hi));
    }
    for (int i = t; i < 56 * 128; i += 256) {   // zero pad rows 1032..1087 (swizzle-invariant)
        fwhi[1032 * 128 + i] = 0;
        fwlo[1032 * 128 + i] = 0;
    }
}

// ---------------- bf16x3 MFMA GEMM via global_load_lds staging ----------------
// Block 64x64, 4 waves 2x2, wave 32x32 = 2x2 MFMA tiles. Block tile (A hi/lo, B hi/lo,
// 64x128 bf16 each = 64 KB) staged straight into LDS with 16B global_load_lds (no VGPR
// round-trip; all 16 DMAs per thread in flight, one vmcnt drain at the barrier).
// Globals are pre-swizzled so the linear copy lands bank-conflict-free for ds_read_b128.
// acc += Ah*Wh + Ah*Wl + Al*Wh.
// MODE 0: dec  -> outF[row*40+col]+dec_b, cols masked < 40
// MODE 1: enc  -> relu(v+enc_b) -> hi/lo bf16 (swizzled) to outH/outL, ld=128
// MODE 2: layer-> col<512: bf16 xh (natural); 512..1023: fp32 res (+res_b); 1024..1031: a_src/a_dst
template<int MODE, int KTILES>
__global__ __launch_bounds__(256)
void gemm3_k(const unsigned short* __restrict__ Ahi, const unsigned short* __restrict__ Alo,
             const unsigned short* __restrict__ Bhi, const unsigned short* __restrict__ Blo,
             const float* __restrict__ bias,
             float* __restrict__ outF, unsigned short* __restrict__ outH,
             unsigned short* __restrict__ outL,
             float* __restrict__ a_src, float* __restrict__ a_dst, int M)
{
    constexpr int K = KTILES * 128;
    __shared__ __align__(16) unsigned short sAh[64 * 128];
    __shared__ __align__(16) unsigned short sAl[64 * 128];
    __shared__ __align__(16) unsigned short sBh[64 * 128];
    __shared__ __align__(16) unsigned short sBl[64 * 128];

    const int tid = threadIdx.x;
    const int lane = tid & 63, wv = tid >> 6;
    const int wr = (wv >> 1) * 32, wc = (wv & 1) * 32;
    const int bm = blockIdx.x * 64, bn = blockIdx.y * 64;
    const int r16 = lane & 15, q4 = lane >> 4;

    f4 acc[2][2];
#pragma unroll
    for (int i = 0; i < 2; ++i)
#pragma unroll
        for (int j = 0; j < 2; ++j) acc[i][j] = (f4){0.f, 0.f, 0.f, 0.f};

    const int ra0 = wr + r16;        // A rows this lane reads ((ra0&7)==((ra0+16)&7))
    const int rb0 = wc + r16;

    for (int kt = 0; kt < KTILES; ++kt) {
        if (kt) __syncthreads();
        // ---- stage: linear copy, 4 16B units per thread per tensor, zero VGPR traffic ----
#pragma unroll
        for (int j = 0; j < 4; ++j) {
            int i = tid + j * 256;                    // unit index 0..1023
            int row = i >> 4, u = i & 15;
            int arow = min(bm + row, M - 1);
            int brow = bn + row;
            size_t ga = (size_t)arow * K + kt * 128 + u * 8;
            size_t gb = (size_t)brow * K + kt * 128 + u * 8;
            int lb = (wv * 64 + j * 256) * 8;         // wave-uniform LDS base (elements)
            gl_lds16(Ahi + ga, sAh + lb);
            gl_lds16(Alo + ga, sAl + lb);
            gl_lds16(Bhi + gb, sBh + lb);
            gl_lds16(Blo + gb, sBl + lb);
        }
        __syncthreads();

        // ---- compute: 4 K-steps of 32, 8 ds_read_b128 + 12 MFMA each ----
#pragma unroll
        for (int ks = 0; ks < 4; ++ks) {
            int u = ks * 4 + q4;
            int oa0 = ra0 * 128 + ((u ^ (ra0 & 7)) * 8);
            int ob0 = rb0 * 128 + ((u ^ (rb0 & 7)) * 8);
            int oa1 = oa0 + 16 * 128;
            int ob1 = ob0 + 16 * 128;
            bf8 A0h = *(const bf8*)(sAh + oa0);
            bf8 A1h = *(const bf8*)(sAh + oa1);
            bf8 A0l = *(const bf8*)(sAl + oa0);
            bf8 A1l = *(const bf8*)(sAl + oa1);
            bf8 B0h = *(const bf8*)(sBh + ob0);
            bf8 B1h = *(const bf8*)(sBh + ob1);
            bf8 B0l = *(const bf8*)(sBl + ob0);
            bf8 B1l = *(const bf8*)(sBl + ob1);

            acc[0][0] = __builtin_amdgcn_mfma_f32_16x16x32_bf16(A0h, B0h, acc[0][0], 0, 0, 0);
            acc[0][1] = __builtin_amdgcn_mfma_f32_16x16x32_bf16(A0h, B1h, acc[0][1], 0, 0, 0);
            acc[1][0] = __builtin_amdgcn_mfma_f32_16x16x32_bf16(A1h, B0h, acc[1][0], 0, 0, 0);
            acc[1][1] = __builtin_amdgcn_mfma_f32_16x16x32_bf16(A1h, B1h, acc[1][1], 0, 0, 0);
            acc[0][0] = __builtin_amdgcn_mfma_f32_16x16x32_bf16(A0h, B0l, acc[0][0], 0, 0, 0);
            acc[0][1] = __builtin_amdgcn_mfma_f32_16x16x32_bf16(A0h, B1l, acc[0][1], 0, 0, 0);
            acc[1][0] = __builtin_amdgcn_mfma_f32_16x16x32_bf16(A1h, B0l, acc[1][0], 0, 0, 0);
            acc[1][1] = __builtin_amdgcn_mfma_f32_16x16x32_bf16(A1h, B1l, acc[1][1], 0, 0, 0);
            acc[0][0] = __builtin_amdgcn_mfma_f32_16x16x32_bf16(A0l, B0h, acc[0][0], 0, 0, 0);
            acc[0][1] = __builtin_amdgcn_mfma_f32_16x16x32_bf16(A0l, B1h, acc[0][1], 0, 0, 0);
            acc[1][0] = __builtin_amdgcn_mfma_f32_16x16x32_bf16(A1l, B0h, acc[1][0], 0, 0, 0);
            acc[1][1] = __builtin_amdgcn_mfma_f32_16x16x32_bf16(A1l, B1h, acc[1][1], 0, 0, 0);
        }
    }

    const int rbase = q4 * 4;
#pragma unroll
    for (int i = 0; i < 2; ++i)
#pragma unroll
        for (int j = 0; j < 2; ++j)
#pragma unroll
            for (int r = 0; r < 4; ++r) {
                int row = bm + wr + i * 16 + rbase + r;
                int col = bn + wc + j * 16 + r16;
                if (row >= M) continue;
                float v = acc[i][j][r];
                if (MODE == 1) {
                    v = fmaxf(v + bias[col], 0.0f);
                    unsigned short h = f2bf(v);
                    int sp = swz(row, col);
                    outH[(size_t)row * 128 + sp] = h;
                    outL[(size_t)row * 128 + sp] = f2bf(v - bf2f(h));
                } else if (MODE == 2) {
                    if (col < 512) {
                        outH[(size_t)row * 512 + col] = f2bf(v);
                    } else if (col < 1024) {
                        outF[(size_t)row * 512 + col - 512] = v + bias[col - 512];
                    } else if (col < 1032) {
                        int h = col - 1024;
                        if (h < 4) a_src[row * 4 + h] = v;
                        else       a_dst[row * 4 + h - 4] = v;
                    }
                } else {
                    if (col < NCLASS)
                        outF[(size_t)row * NCLASS + col] = v + bias[col];
                }
            }
}

// ---------------- per-edge unnormalized softmax weights (head-major) + per-node sums ------
__global__ __launch_bounds__(256)
void alpha_k(const int* __restrict__ row_ptr, const int* __restrict__ csr,
             const float* __restrict__ a_src, const float* __restrict__ a_dst,
             float* __restrict__ t, float* __restrict__ ssum)
{
    int wave = threadIdx.x >> 6, lane = threadIdx.x & 63;
    int d = blockIdx.x * 4 + wave;
    if (d >= NN) return;
    int beg = row_ptr[d], end = row_ptr[d + 1];
    float4 ad = *(const float4*)(a_dst + d * 4);
    float s0 = 0.f, s1 = 0.f, s2 = 0.f, s3 = 0.f;
    for (int e = beg + lane; e < end; e += 64) {
        int s = csr[e];
        float4 as = *(const float4*)(a_src + s * 4);
        float t0 = expf(leaky02(as.x + ad.x));
        float t1 = expf(leaky02(as.y + ad.y));
        float t2 = expf(leaky02(as.z + ad.z));
        float t3 = expf(leaky02(as.w + ad.w));
        t[0 * EP + e] = t0;
        t[1 * EP + e] = t1;
        t[2 * EP + e] = t2;
        t[3 * EP + e] = t3;
        s0 += t0; s1 += t1; s2 += t2; s3 += t3;
    }
#pragma unroll
    for (int off = 32; off >= 1; off >>= 1) {
        s0 += __shfl_xor(s0, off);
        s1 += __shfl_xor(s1, off);
        s2 += __shfl_xor(s2, off);
        s3 += __shfl_xor(s3, off);
    }
    if (lane == 0) *(float4*)(ssum + d * 4) = make_float4(s0, s1, s2, s3);
}

// ---------------- gather + residual + ELU + head-mean -> X (hi/lo bf16, swizzled) ----------
__global__ __launch_bounds__(256)
void agg_k(const int* __restrict__ row_ptr, const int* __restrict__ csr,
           const float* __restrict__ t, const float* __restrict__ ssum,
           const unsigned short* __restrict__ xh_b, const float* __restrict__ res,
           const float* __restrict__ gat_b,
           unsigned short* __restrict__ Xhi, unsigned short* __restrict__ Xlo)
{
    int wave = threadIdx.x >> 6, lane = threadIdx.x & 63;
    int d = blockIdx.x * 4 + wave;
    if (d >= NN) return;
    int beg = row_ptr[d], end = row_ptr[d + 1];
    int hl = lane >> 4;                       // head owned by this lane's cols
    int cb = lane * 8;                        // 8 bf16 cols = 16 B per lane
    const float* th = t + (size_t)hl * EP;

    float acc[8];
#pragma unroll
    for (int k = 0; k < 8; ++k) acc[k] = 0.0f;

    int e = beg;
    for (; e + 4 <= end; e += 4) {
        int s0v = csr[e + 0], s1v = csr[e + 1], s2v = csr[e + 2], s3v = csr[e + 3];
        float w0 = th[e + 0], w1 = th[e + 1], w2 = th[e + 2], w3 = th[e + 3];
        u16x8 v0 = *(const u16x8*)(xh_b + (size_t)s0v * HF + cb);
        u16x8 v1 = *(const u16x8*)(xh_b + (size_t)s1v * HF + cb);
        u16x8 v2 = *(const u16x8*)(xh_b + (size_t)s2v * HF + cb);
        u16x8 v3 = *(const u16x8*)(xh_b + (size_t)s3v * HF + cb);
#pragma unroll
        for (int k = 0; k < 8; ++k) acc[k] = fmaf(w0, bf2f(v0[k]), acc[k]);
#pragma unroll
        for (int k = 0; k < 8; ++k) acc[k] = fmaf(w1, bf2f(v1[k]), acc[k]);
#pragma unroll
        for (int k = 0; k < 8; ++k) acc[k] = fmaf(w2, bf2f(v2[k]), acc[k]);
#pragma unroll
        for (int k = 0; k < 8; ++k) acc[k] = fmaf(w3, bf2f(v3[k]), acc[k]);
    }
    for (; e < end; ++e) {
        int s = csr[e];
        float w = th[e];
        u16x8 v = *(const u16x8*)(xh_b + (size_t)s * HF + cb);
#pragma unroll
        for (int k = 0; k < 8; ++k) acc[k] = fmaf(w, bf2f(v[k]), acc[k]);
    }

    float inv = 1.0f / ssum[d * 4 + hl];
    const float* rr = res + (size_t)d * HF + cb;
    const float* gb = gat_b + cb;
    float u[8];
#pragma unroll
    for (int k = 0; k < 8; ++k) {
        float v = fmaf(acc[k], inv, gb[k] + rr[k]);
        u[k] = (v > 0.0f) ? v : expm1f(v);
    }
    float z0 = (u[0] + u[1] + u[2] + u[3]) * 0.25f;
    float z1 = (u[4] + u[5] + u[6] + u[7]) * 0.25f;
    unsigned short h0 = f2bf(z0), h1 = f2bf(z1);
    unsigned short l0 = f2bf(z0 - bf2f(h0)), l1 = f2bf(z1 - bf2f(h1));
    int pos = swz(d, lane * 2);               // 2 consecutive cols stay in one unit
    size_t idx = (size_t)d * NHID + pos;
    *(unsigned*)(Xhi + idx) = ((unsigned)h1 << 16) | h0;
    *(unsigned*)(Xlo + idx) = ((unsigned)l1 << 16) | l0;
}

// ---------------- launcher ----------------
extern "C" void kernel_launch(void* const* d_in, const int* in_sizes, int n_in,
                              void* d_out, int out_size, void* d_ws, size_t ws_size,
                              hipStream_t stream)
{
    const float* x       = (const float*)d_in[0];
    const int*   ei      = (const int*)d_in[1];
    const float* enc_w   = (const float*)d_in[2];
    const float* enc_b   = (const float*)d_in[3];
    const float* res_w   = (const float*)d_in[4];
    const float* res_b   = (const float*)d_in[5];
    const float* gat_w   = (const float*)d_in[6];
    const float* att_src = (const float*)d_in[7];
    const float* att_dst = (const float*)d_in[8];
    const float* gat_b   = (const float*)d_in[9];
    const float* dec_w   = (const float*)d_in[10];
    const float* dec_b   = (const float*)d_in[11];
    float* out = (float*)d_out;

    char* p = (char*)d_ws;
    auto alloc = [&](size_t bytes) -> void* {
        void* r = (void*)p;
        p += (bytes + 255) & ~(size_t)255;
        return r;
    };
    float* res    = (float*)alloc(5120000 * 4);            // [N,512] fp32
    float* t      = (float*)alloc(4 * EP * 4);             // [4][EP] head-major
    float* a_src  = (float*)alloc(40000 * 4);
    float* a_dst  = (float*)alloc(40000 * 4);
    float* ssum   = (float*)alloc(40000 * 4);
    unsigned short* xh_b = (unsigned short*)alloc(5120000 * 2);     // [N,512] bf16 (natural)
    unsigned short* Xhi  = (unsigned short*)alloc(1280000 * 2);     // [N,128] bf16 (swizzled)
    unsigned short* Xlo  = (unsigned short*)alloc(1280000 * 2);
    unsigned short* xhi  = (unsigned short*)alloc(2560000 * 2);     // x hi/lo [N,256] (swizzled)
    unsigned short* xlo  = (unsigned short*)alloc(2560000 * 2);
    unsigned short* ewhi = (unsigned short*)alloc(32768 * 2);       // enc_w [128,256] (swizzled)
    unsigned short* ewlo = (unsigned short*)alloc(32768 * 2);
    unsigned short* fwhi = (unsigned short*)alloc(FCOLS * 128 * 2); // [1088,128] (swizzled)
    unsigned short* fwlo = (unsigned short*)alloc(FCOLS * 128 * 2);
    int* row_ptr = (int*)alloc(10004 * 4);
    int* csr     = (int*)alloc(170000 * 4);
    // ---- zero zone (single memset): padded dec W + cnt + cursor ----
    char* zbase = p;
    unsigned short* dwhi = (unsigned short*)alloc(8192 * 2);        // [64,128] padded (swizzled)
    unsigned short* dwlo = (unsigned short*)alloc(8192 * 2);
    int* cnt    = (int*)alloc(10000 * 4);
    int* cursor = (int*)alloc(10000 * 4);
    size_t zbytes = (size_t)(p - zbase);

    hipMemsetAsync(zbase, 0, zbytes, stream);

    // CSR build (graph static across both layers)
    int eb = (EP + 255) / 256;
    count_edges_k<<<eb, 256, 0, stream>>>(ei, cnt);
    scan_k<<<1, 256, 0, stream>>>(cnt, row_ptr);
    fill_csr_k<<<eb, 256, 0, stream>>>(ei, row_ptr, cursor, csr);

    // hi/lo conversions (x + all weights), 8 elems/thread, swizzled stores
    cvt_all_k<<<(C_DW / 8 + 255) / 256, 256, 0, stream>>>(
        x, enc_w, gat_w, res_w, dec_w,
        xhi, xlo, ewhi, ewlo, fwhi, fwlo, dwhi, dwlo);
    // fused attention weight rows (fw rows 1024..1031 + zero tail)
    attw_k<<<1, 256, 0, stream>>>(gat_w, att_src, att_dst, fwhi, fwlo);

    // encoder: X = relu(x @ enc_w.T + enc_b) -> hi/lo bf16  (K=256 -> 2 K-tiles)
    gemm3_k<1, 2><<<dim3(157, 2), 256, 0, stream>>>(
        xhi, xlo, ewhi, ewlo, enc_b, nullptr, Xhi, Xlo, nullptr, nullptr, NN);

    for (int layer = 0; layer < 2; ++layer) {
        // fused [xh | res | a_src a_dst] = X @ [gat_w; res_w; As; Ad].T
        gemm3_k<2, 1><<<dim3(157, 17), 256, 0, stream>>>(
            Xhi, Xlo, fwhi, fwlo, res_b, res, xh_b, nullptr, a_src, a_dst, NN);
        alpha_k<<<2500, 256, 0, stream>>>(row_ptr, csr, a_src, a_dst, t, ssum);
        agg_k<<<2500, 256, 0, stream>>>(row_ptr, csr, t, ssum, xh_b, res, gat_b, Xhi, Xlo);
    }

    // decoder: out = X @ dec_w.T + dec_b
    gemm3_k<0, 1><<<dim3(157, 1), 256, 0, stream>>>(
        Xhi, Xlo, dwhi, dwlo, dec_b, out, nullptr, nullptr, nullptr, nullptr, NN);
}

// Round 7
// 277.130 us; speedup vs baseline: 1.2716x; 1.0599x over previous
//
#include <hip/hip_runtime.h>
#include <math.h>

#define NN 10000
#define EE 160000
#define EP 170000          // EE + NN self loops
#define NFEAT 256
#define NHID 128
#define NH 4
#define HF 512             // NH * NHID
#define NCLASS 40
#define FCOLS 1088         // 512 xh + 512 res + 8 attn + 56 pad

typedef __attribute__((ext_vector_type(8))) short bf8;     // 8 bf16 (4 VGPR) MFMA frag
typedef __attribute__((ext_vector_type(8))) unsigned short u16x8;
typedef __attribute__((ext_vector_type(4))) float f4;

__device__ __forceinline__ float leaky02(float x) { return x >= 0.0f ? x : 0.2f * x; }

__device__ __forceinline__ unsigned short f2bf(float f) {   // RNE
    unsigned u = __builtin_bit_cast(unsigned, f);
    unsigned r = (u + 0x7FFF + ((u >> 16) & 1)) >> 16;
    return (unsigned short)r;
}
__device__ __forceinline__ float bf2f(unsigned short h) {
    return __builtin_bit_cast(float, (unsigned)h << 16);
}

// Bank-swizzled element position within a row of length K (baked into GLOBAL layout
// of all MFMA operands so that global->LDS staging is a LINEAR copy usable by
// global_load_lds). Unit u=c>>3 goes to physical unit u^(row&7).
__device__ __forceinline__ int swz(int row, int c) {
    return ((((c >> 3) ^ (row & 7)) << 3) | (c & 7));
}

// 16B global -> LDS direct DMA (lane l's 16B lands at ldsbase + l*16)
__device__ __forceinline__ void gl_lds16(const unsigned short* g, unsigned short* l)
{
    __builtin_amdgcn_global_load_lds(
        (const __attribute__((address_space(1))) unsigned int*)g,
        (__attribute__((address_space(3))) unsigned int*)l, 16, 0, 0);
}

// ---------------- CSR build ----------------
__global__ __launch_bounds__(256)
void count_edges_k(const int* __restrict__ ei, int* __restrict__ cnt)
{
    int e = blockIdx.x * 256 + threadIdx.x;
    if (e >= EP) return;
    int d = (e < EE) ? ei[EE + e] : (e - EE);
    atomicAdd(&cnt[d], 1);
}

__global__ __launch_bounds__(1024)
void scan_k(const int* __restrict__ cnt, int* __restrict__ row_ptr)
{
    __shared__ int sm[1024];
    int t = threadIdx.x;
    int i0 = t * 10, i1 = min(i0 + 10, NN);
    int part = 0;
    for (int i = i0; i < i1; ++i) part += cnt[i];
    sm[t] = part;
    __syncthreads();
    for (int off = 1; off < 1024; off <<= 1) {
        int v = (t >= off) ? sm[t - off] : 0;
        __syncthreads();
        sm[t] += v;
        __syncthreads();
    }
    int run = sm[t] - part;             // exclusive prefix
    for (int i = i0; i < i1; ++i) { row_ptr[i] = run; run += cnt[i]; }
    if (t == 1023) row_ptr[NN] = run;
}

__global__ __launch_bounds__(256)
void fill_csr_k(const int* __restrict__ ei, const int* __restrict__ row_ptr,
                int* __restrict__ cursor, int* __restrict__ csr)
{
    int e = blockIdx.x * 256 + threadIdx.x;
    if (e >= EP) return;
    int s, d;
    if (e < EE) { s = ei[e]; d = ei[EE + e]; } else { s = e - EE; d = s; }
    int pos = row_ptr[d] + atomicAdd(&cursor[d], 1);
    csr[pos] = s;
}

// ---------------- hi/lo bf16 conversion of x + all weights (swizzled layout) ----------------
#define C_X   2560000
#define C_EW  (C_X + 32768)
#define C_FW  (C_EW + 131072)      // gat_w (65536) + res_w (65536) -> fw rows 0..1023
#define C_DW  (C_FW + 5120)

__global__ __launch_bounds__(256)
void cvt_all_k(const float* __restrict__ x, const float* __restrict__ enc_w,
               const float* __restrict__ gat_w, const float* __restrict__ res_w,
               const float* __restrict__ dec_w,
               unsigned short* __restrict__ xhi, unsigned short* __restrict__ xlo,
               unsigned short* __restrict__ ewhi, unsigned short* __restrict__ ewlo,
               unsigned short* __restrict__ fwhi, unsigned short* __restrict__ fwlo,
               unsigned short* __restrict__ dwhi, unsigned short* __restrict__ dwlo)
{
    int iu = blockIdx.x * 256 + threadIdx.x;    // 8-element unit index
    int i = iu * 8;
    if (i >= C_DW) return;
    const float* src = nullptr; unsigned short *ph, *pl; int j, row, c, Kd;
    if (i < C_X)       { j = i;        src = x;     ph = xhi;  pl = xlo;
                         row = j >> 8; c = j & 255; Kd = 256; }
    else if (i < C_EW) { j = i - C_X;  src = enc_w; ph = ewhi; pl = ewlo;
                         row = j >> 8; c = j & 255; Kd = 256; }
    else if (i < C_FW) { j = i - C_EW; ph = fwhi;   pl = fwlo;
                         row = j >> 7; c = j & 127; Kd = 128; }
    else               { j = i - C_FW; src = dec_w; ph = dwhi; pl = dwlo;
                         row = j >> 7; c = j & 127; Kd = 128; }

    float4 v0, v1;
    if (src) { v0 = *(const float4*)(src + j); v1 = *(const float4*)(src + j + 4); }
    else {
        const float* s2 = (j < 65536) ? (gat_w + j) : (res_w + j - 65536);
        v0 = *(const float4*)s2; v1 = *(const float4*)(s2 + 4);
    }
    float vv[8] = {v0.x, v0.y, v0.z, v0.w, v1.x, v1.y, v1.z, v1.w};
    unsigned short hs[8], ls[8];
#pragma unroll
    for (int k = 0; k < 8; ++k) {
        hs[k] = f2bf(vv[k]);
        ls[k] = f2bf(vv[k] - bf2f(hs[k]));
    }
    int out = row * Kd + swz(row, c);   // c multiple of 8 -> 8 contiguous elements
    *(u16x8*)(ph + out) = *(u16x8*)hs;
    *(u16x8*)(pl + out) = *(u16x8*)ls;
}

// ---------------- fused attention weight rows: fw rows 1024..1031 (+ zero tail) ----------------
// Block b (of 8) computes row R = 1024 + (b>=4?4:0)+(b&3): out[k] = sum_c gat_w[h*128+c][k]*att[h*128+c].
// Lanes indexed by k -> each c-iteration reads a contiguous 256B slab per wave (coalesced).
// Round-6 version was ONE block with stride-512B per-lane reads: single-CU latency-bound.
__global__ __launch_bounds__(256)
void attw_k(const float* __restrict__ gat_w, const float* __restrict__ att_src,
            const float* __restrict__ att_dst,
            unsigned short* __restrict__ fwhi, unsigned short* __restrict__ fwlo)
{
    __shared__ float sm[256];
    int b = blockIdx.x;                 // 0..7
    int is_dst = b >> 2, h = b & 3;
    const float* att = is_dst ? att_dst : att_src;
    int t = threadIdx.x;
    int k = t & 127, half = t >> 7;     // half-range of c per 128-thread group
    float s = 0.0f;
#pragma unroll 4
    for (int c = half * 64; c < half * 64 + 64; ++c)
        s = fmaf(gat_w[(size_t)(h * 128 + c) * 128 + k], att[h * 128 + c], s);
    sm[t] = s;
    __syncthreads();
    if (t < 128) {
        float v = sm[t] + sm[t + 128];
        int R = 1024 + is_dst * 4 + h;
        size_t o = (size_t)R * 128 + swz(R, k);
        unsigned short hi = f2bf(v);
        fwhi[o] = hi;
        fwlo[o] = f2bf(v - bf2f(hi));
    }
    // zero pad rows 1032..1087 (7168 elems, 896 per block; swizzle-invariant)
    for (int i = b * 896 + t; i < (b + 1) * 896; i += 256) {
        fwhi[1032 * 128 + i] = 0;
        fwlo[1032 * 128 + i] = 0;
    }
}

// ---------------- bf16x3 MFMA GEMM via global_load_lds staging ----------------
// Block 64x64, 4 waves 2x2, wave 32x32 = 2x2 MFMA tiles. Block tile (A hi/lo, B hi/lo,
// 64x128 bf16 each = 64 KB) staged straight into LDS with 16B global_load_lds.
// Globals pre-swizzled so the linear copy is bank-conflict-free for ds_read_b128.
// acc += Ah*Wh + Ah*Wl + Al*Wh.
// MODE 0: dec  -> outF[row*40+col]+dec_b, cols masked < 40
// MODE 1: enc  -> relu(v+enc_b) -> hi/lo bf16 (swizzled) to outH/outL, ld=128
// MODE 2: layer-> col<512: bf16 xh (natural); 512..1023: fp32 res (+res_b); 1024..1031: a_src/a_dst
template<int MODE, int KTILES>
__global__ __launch_bounds__(256)
void gemm3_k(const unsigned short* __restrict__ Ahi, const unsigned short* __restrict__ Alo,
             const unsigned short* __restrict__ Bhi, const unsigned short* __restrict__ Blo,
             const float* __restrict__ bias,
             float* __restrict__ outF, unsigned short* __restrict__ outH,
             unsigned short* __restrict__ outL,
             float* __restrict__ a_src, float* __restrict__ a_dst, int M)
{
    constexpr int K = KTILES * 128;
    __shared__ __align__(16) unsigned short sAh[64 * 128];
    __shared__ __align__(16) unsigned short sAl[64 * 128];
    __shared__ __align__(16) unsigned short sBh[64 * 128];
    __shared__ __align__(16) unsigned short sBl[64 * 128];

    const int tid = threadIdx.x;
    const int lane = tid & 63, wv = tid >> 6;
    const int wr = (wv >> 1) * 32, wc = (wv & 1) * 32;
    const int bm = blockIdx.x * 64, bn = blockIdx.y * 64;
    const int r16 = lane & 15, q4 = lane >> 4;

    f4 acc[2][2];
#pragma unroll
    for (int i = 0; i < 2; ++i)
#pragma unroll
        for (int j = 0; j < 2; ++j) acc[i][j] = (f4){0.f, 0.f, 0.f, 0.f};

    const int ra0 = wr + r16;        // A rows this lane reads ((ra0&7)==((ra0+16)&7))
    const int rb0 = wc + r16;

    for (int kt = 0; kt < KTILES; ++kt) {
        if (kt) __syncthreads();
        // ---- stage: linear copy, 4 16B units per thread per tensor, zero VGPR traffic ----
#pragma unroll
        for (int j = 0; j < 4; ++j) {
            int i = tid + j * 256;                    // unit index 0..1023
            int row = i >> 4, u = i & 15;
            int arow = min(bm + row, M - 1);
            int brow = bn + row;
            size_t ga = (size_t)arow * K + kt * 128 + u * 8;
            size_t gb = (size_t)brow * K + kt * 128 + u * 8;
            int lb = (wv * 64 + j * 256) * 8;         // wave-uniform LDS base (elements)
            gl_lds16(Ahi + ga, sAh + lb);
            gl_lds16(Alo + ga, sAl + lb);
            gl_lds16(Bhi + gb, sBh + lb);
            gl_lds16(Blo + gb, sBl + lb);
        }
        __syncthreads();

        // ---- compute: 4 K-steps of 32, 8 ds_read_b128 + 12 MFMA each ----
#pragma unroll
        for (int ks = 0; ks < 4; ++ks) {
            int u = ks * 4 + q4;
            int oa0 = ra0 * 128 + ((u ^ (ra0 & 7)) * 8);
            int ob0 = rb0 * 128 + ((u ^ (rb0 & 7)) * 8);
            int oa1 = oa0 + 16 * 128;
            int ob1 = ob0 + 16 * 128;
            bf8 A0h = *(const bf8*)(sAh + oa0);
            bf8 A1h = *(const bf8*)(sAh + oa1);
            bf8 A0l = *(const bf8*)(sAl + oa0);
            bf8 A1l = *(const bf8*)(sAl + oa1);
            bf8 B0h = *(const bf8*)(sBh + ob0);
            bf8 B1h = *(const bf8*)(sBh + ob1);
            bf8 B0l = *(const bf8*)(sBl + ob0);
            bf8 B1l = *(const bf8*)(sBl + ob1);

            acc[0][0] = __builtin_amdgcn_mfma_f32_16x16x32_bf16(A0h, B0h, acc[0][0], 0, 0, 0);
            acc[0][1] = __builtin_amdgcn_mfma_f32_16x16x32_bf16(A0h, B1h, acc[0][1], 0, 0, 0);
            acc[1][0] = __builtin_amdgcn_mfma_f32_16x16x32_bf16(A1h, B0h, acc[1][0], 0, 0, 0);
            acc[1][1] = __builtin_amdgcn_mfma_f32_16x16x32_bf16(A1h, B1h, acc[1][1], 0, 0, 0);
            acc[0][0] = __builtin_amdgcn_mfma_f32_16x16x32_bf16(A0h, B0l, acc[0][0], 0, 0, 0);
            acc[0][1] = __builtin_amdgcn_mfma_f32_16x16x32_bf16(A0h, B1l, acc[0][1], 0, 0, 0);
            acc[1][0] = __builtin_amdgcn_mfma_f32_16x16x32_bf16(A1h, B0l, acc[1][0], 0, 0, 0);
            acc[1][1] = __builtin_amdgcn_mfma_f32_16x16x32_bf16(A1h, B1l, acc[1][1], 0, 0, 0);
            acc[0][0] = __builtin_amdgcn_mfma_f32_16x16x32_bf16(A0l, B0h, acc[0][0], 0, 0, 0);
            acc[0][1] = __builtin_amdgcn_mfma_f32_16x16x32_bf16(A0l, B1h, acc[0][1], 0, 0, 0);
            acc[1][0] = __builtin_amdgcn_mfma_f32_16x16x32_bf16(A1l, B0h, acc[1][0], 0, 0, 0);
            acc[1][1] = __builtin_amdgcn_mfma_f32_16x16x32_bf16(A1l, B1h, acc[1][1], 0, 0, 0);
        }
    }

    const int rbase = q4 * 4;
#pragma unroll
    for (int i = 0; i < 2; ++i)
#pragma unroll
        for (int j = 0; j < 2; ++j)
#pragma unroll
            for (int r = 0; r < 4; ++r) {
                int row = bm + wr + i * 16 + rbase + r;
                int col = bn + wc + j * 16 + r16;
                if (row >= M) continue;
                float v = acc[i][j][r];
                if (MODE == 1) {
                    v = fmaxf(v + bias[col], 0.0f);
                    unsigned short h = f2bf(v);
                    int sp = swz(row, col);
                    outH[(size_t)row * 128 + sp] = h;
                    outL[(size_t)row * 128 + sp] = f2bf(v - bf2f(h));
                } else if (MODE == 2) {
                    if (col < 512) {
                        outH[(size_t)row * 512 + col] = f2bf(v);
                    } else if (col < 1024) {
                        outF[(size_t)row * 512 + col - 512] = v + bias[col - 512];
                    } else if (col < 1032) {
                        int h = col - 1024;
                        if (h < 4) a_src[row * 4 + h] = v;
                        else       a_dst[row * 4 + h - 4] = v;
                    }
                } else {
                    if (col < NCLASS)
                        outF[(size_t)row * NCLASS + col] = v + bias[col];
                }
            }
}

// ---------------- per-edge unnormalized softmax weights (head-major) + per-node sums ------
// 16-lane group per node (avg degree ~17 -> near-full lane occupancy vs wave-per-node).
__global__ __launch_bounds__(256)
void alpha_k(const int* __restrict__ row_ptr, const int* __restrict__ csr,
             const float* __restrict__ a_src, const float* __restrict__ a_dst,
             float* __restrict__ t, float* __restrict__ ssum)
{
    int tid = threadIdx.x;
    int grp = tid >> 4, l16 = tid & 15;       // 16 groups per block
    int d = blockIdx.x * 16 + grp;
    if (d >= NN) return;
    int beg = row_ptr[d], end = row_ptr[d + 1];
    float4 ad = *(const float4*)(a_dst + d * 4);
    float s0 = 0.f, s1 = 0.f, s2 = 0.f, s3 = 0.f;
    for (int e = beg + l16; e < end; e += 16) {
        int s = csr[e];
        float4 as = *(const float4*)(a_src + s * 4);
        float t0 = expf(leaky02(as.x + ad.x));
        float t1 = expf(leaky02(as.y + ad.y));
        float t2 = expf(leaky02(as.z + ad.z));
        float t3 = expf(leaky02(as.w + ad.w));
        t[0 * EP + e] = t0;
        t[1 * EP + e] = t1;
        t[2 * EP + e] = t2;
        t[3 * EP + e] = t3;
        s0 += t0; s1 += t1; s2 += t2; s3 += t3;
    }
#pragma unroll
    for (int off = 8; off >= 1; off >>= 1) {   // xor<16 stays within the 16-lane group
        s0 += __shfl_xor(s0, off);
        s1 += __shfl_xor(s1, off);
        s2 += __shfl_xor(s2, off);
        s3 += __shfl_xor(s3, off);
    }
    if (l16 == 0) *(float4*)(ssum + d * 4) = make_float4(s0, s1, s2, s3);
}

// ---------------- gather + residual + ELU + head-mean -> X (hi/lo bf16, swizzled) ----------
__global__ __launch_bounds__(256)
void agg_k(const int* __restrict__ row_ptr, const int* __restrict__ csr,
           const float* __restrict__ t, const float* __restrict__ ssum,
           const unsigned short* __restrict__ xh_b, const float* __restrict__ res,
           const float* __restrict__ gat_b,
           unsigned short* __restrict__ Xhi, unsigned short* __restrict__ Xlo)
{
    int wave = threadIdx.x >> 6, lane = threadIdx.x & 63;
    int d = blockIdx.x * 4 + wave;
    if (d >= NN) return;
    int beg = row_ptr[d], end = row_ptr[d + 1];
    int hl = lane >> 4;                       // head owned by this lane's cols
    int cb = lane * 8;                        // 8 bf16 cols = 16 B per lane
    const float* th = t + (size_t)hl * EP;

    float acc[8];
#pragma unroll
    for (int k = 0; k < 8; ++k) acc[k] = 0.0f;

    int e = beg;
    for (; e + 8 <= end; e += 8) {            // 8 gathers in flight per wave
        int sv[8]; float w[8]; u16x8 v[8];
#pragma unroll
        for (int q = 0; q < 8; ++q) { sv[q] = csr[e + q]; w[q] = th[e + q]; }
#pragma unroll
        for (int q = 0; q < 8; ++q) v[q] = *(const u16x8*)(xh_b + (size_t)sv[q] * HF + cb);
#pragma unroll
        for (int q = 0; q < 8; ++q)
#pragma unroll
            for (int k = 0; k < 8; ++k) acc[k] = fmaf(w[q], bf2f(v[q][k]), acc[k]);
    }
    for (; e + 4 <= end; e += 4) {
        int sv[4]; float w[4]; u16x8 v[4];
#pragma unroll
        for (int q = 0; q < 4; ++q) { sv[q] = csr[e + q]; w[q] = th[e + q]; }
#pragma unroll
        for (int q = 0; q < 4; ++q) v[q] = *(const u16x8*)(xh_b + (size_t)sv[q] * HF + cb);
#pragma unroll
        for (int q = 0; q < 4; ++q)
#pragma unroll
            for (int k = 0; k < 8; ++k) acc[k] = fmaf(w[q], bf2f(v[q][k]), acc[k]);
    }
    for (; e < end; ++e) {
        int s = csr[e];
        float w = th[e];
        u16x8 v = *(const u16x8*)(xh_b + (size_t)s * HF + cb);
#pragma unroll
        for (int k = 0; k < 8; ++k) acc[k] = fmaf(w, bf2f(v[k]), acc[k]);
    }

    float inv = 1.0f / ssum[d * 4 + hl];
    const float* rr = res + (size_t)d * HF + cb;
    const float* gb = gat_b + cb;
    float u[8];
#pragma unroll
    for (int k = 0; k < 8; ++k) {
        float v = fmaf(acc[k], inv, gb[k] + rr[k]);
        u[k] = (v > 0.0f) ? v : expm1f(v);
    }
    float z0 = (u[0] + u[1] + u[2] + u[3]) * 0.25f;
    float z1 = (u[4] + u[5] + u[6] + u[7]) * 0.25f;
    unsigned short h0 = f2bf(z0), h1 = f2bf(z1);
    unsigned short l0 = f2bf(z0 - bf2f(h0)), l1 = f2bf(z1 - bf2f(h1));
    int pos = swz(d, lane * 2);               // 2 consecutive cols stay in one unit
    size_t idx = (size_t)d * NHID + pos;
    *(unsigned*)(Xhi + idx) = ((unsigned)h1 << 16) | h0;
    *(unsigned*)(Xlo + idx) = ((unsigned)l1 << 16) | l0;
}

// ---------------- launcher ----------------
extern "C" void kernel_launch(void* const* d_in, const int* in_sizes, int n_in,
                              void* d_out, int out_size, void* d_ws, size_t ws_size,
                              hipStream_t stream)
{
    const float* x       = (const float*)d_in[0];
    const int*   ei      = (const int*)d_in[1];
    const float* enc_w   = (const float*)d_in[2];
    const float* enc_b   = (const float*)d_in[3];
    const float* res_w   = (const float*)d_in[4];
    const float* res_b   = (const float*)d_in[5];
    const float* gat_w   = (const float*)d_in[6];
    const float* att_src = (const float*)d_in[7];
    const float* att_dst = (const float*)d_in[8];
    const float* gat_b   = (const float*)d_in[9];
    const float* dec_w   = (const float*)d_in[10];
    const float* dec_b   = (const float*)d_in[11];
    float* out = (float*)d_out;

    char* p = (char*)d_ws;
    auto alloc = [&](size_t bytes) -> void* {
        void* r = (void*)p;
        p += (bytes + 255) & ~(size_t)255;
        return r;
    };
    float* res    = (float*)alloc(5120000 * 4);            // [N,512] fp32
    float* t      = (float*)alloc(4 * EP * 4);             // [4][EP] head-major
    float* a_src  = (float*)alloc(40000 * 4);
    float* a_dst  = (float*)alloc(40000 * 4);
    float* ssum   = (float*)alloc(40000 * 4);
    unsigned short* xh_b = (unsigned short*)alloc(5120000 * 2);     // [N,512] bf16 (natural)
    unsigned short* Xhi  = (unsigned short*)alloc(1280000 * 2);     // [N,128] bf16 (swizzled)
    unsigned short* Xlo  = (unsigned short*)alloc(1280000 * 2);
    unsigned short* xhi  = (unsigned short*)alloc(2560000 * 2);     // x hi/lo [N,256] (swizzled)
    unsigned short* xlo  = (unsigned short*)alloc(2560000 * 2);
    unsigned short* ewhi = (unsigned short*)alloc(32768 * 2);       // enc_w [128,256] (swizzled)
    unsigned short* ewlo = (unsigned short*)alloc(32768 * 2);
    unsigned short* fwhi = (unsigned short*)alloc(FCOLS * 128 * 2); // [1088,128] (swizzled)
    unsigned short* fwlo = (unsigned short*)alloc(FCOLS * 128 * 2);
    int* row_ptr = (int*)alloc(10004 * 4);
    int* csr     = (int*)alloc(170000 * 4);
    // ---- zero zone (single memset): padded dec W + cnt + cursor ----
    char* zbase = p;
    unsigned short* dwhi = (unsigned short*)alloc(8192 * 2);        // [64,128] padded (swizzled)
    unsigned short* dwlo = (unsigned short*)alloc(8192 * 2);
    int* cnt    = (int*)alloc(10000 * 4);
    int* cursor = (int*)alloc(10000 * 4);
    size_t zbytes = (size_t)(p - zbase);

    hipMemsetAsync(zbase, 0, zbytes, stream);

    // CSR build (graph static across both layers)
    int eb = (EP + 255) / 256;
    count_edges_k<<<eb, 256, 0, stream>>>(ei, cnt);
    scan_k<<<1, 1024, 0, stream>>>(cnt, row_ptr);
    fill_csr_k<<<eb, 256, 0, stream>>>(ei, row_ptr, cursor, csr);

    // hi/lo conversions (x + all weights), 8 elems/thread, swizzled stores
    cvt_all_k<<<(C_DW / 8 + 255) / 256, 256, 0, stream>>>(
        x, enc_w, gat_w, res_w, dec_w,
        xhi, xlo, ewhi, ewlo, fwhi, fwlo, dwhi, dwlo);
    // fused attention weight rows (fw rows 1024..1031 + zero tail), 8 coalesced blocks
    attw_k<<<8, 256, 0, stream>>>(gat_w, att_src, att_dst, fwhi, fwlo);

    // encoder: X = relu(x @ enc_w.T + enc_b) -> hi/lo bf16  (K=256 -> 2 K-tiles)
    gemm3_k<1, 2><<<dim3(157, 2), 256, 0, stream>>>(
        xhi, xlo, ewhi, ewlo, enc_b, nullptr, Xhi, Xlo, nullptr, nullptr, NN);

    for (int layer = 0; layer < 2; ++layer) {
        // fused [xh | res | a_src a_dst] = X @ [gat_w; res_w; As; Ad].T
        gemm3_k<2, 1><<<dim3(157, 17), 256, 0, stream>>>(
            Xhi, Xlo, fwhi, fwlo, res_b, res, xh_b, nullptr, a_src, a_dst, NN);
        alpha_k<<<625, 256, 0, stream>>>(row_ptr, csr, a_src, a_dst, t, ssum);
        agg_k<<<2500, 256, 0, stream>>>(row_ptr, csr, t, ssum, xh_b, res, gat_b, Xhi, Xlo);
    }

    // decoder: out = X @ dec_w.T + dec_b
    gemm3_k<0, 1><<<dim3(157, 1), 256, 0, stream>>>(
        Xhi, Xlo, dwhi, dwlo, dec_b, out, nullptr, nullptr, nullptr, nullptr, NN);
}

// Round 8
// 252.877 us; speedup vs baseline: 1.3935x; 1.0959x over previous
//
#include <hip/hip_runtime.h>
#include <math.h>

#define NN 10000
#define EE 160000
#define EP 170000          // EE + NN self loops
#define NFEAT 256
#define NHID 128
#define NH 4
#define HF 512             // NH * NHID
#define NCLASS 40
#define FCOLS 1088         // 512 xh + 512 res + 8 attn + 56 pad

typedef __attribute__((ext_vector_type(8))) short bf8;     // 8 bf16 (4 VGPR) MFMA frag
typedef __attribute__((ext_vector_type(8))) unsigned short u16x8;
typedef __attribute__((ext_vector_type(4))) float f4;

__device__ __forceinline__ float leaky02(float x) { return x >= 0.0f ? x : 0.2f * x; }

__device__ __forceinline__ unsigned short f2bf(float f) {   // RNE
    unsigned u = __builtin_bit_cast(unsigned, f);
    unsigned r = (u + 0x7FFF + ((u >> 16) & 1)) >> 16;
    return (unsigned short)r;
}
__device__ __forceinline__ float bf2f(unsigned short h) {
    return __builtin_bit_cast(float, (unsigned)h << 16);
}

// Bank-swizzled element position within a row of length K (baked into GLOBAL layout
// of all MFMA operands so that global->LDS staging is a LINEAR copy usable by
// global_load_lds). Unit u=c>>3 goes to physical unit u^(row&7).
__device__ __forceinline__ int swz(int row, int c) {
    return ((((c >> 3) ^ (row & 7)) << 3) | (c & 7));
}

// 16B global -> LDS direct DMA
__device__ __forceinline__ void gl_lds16(const unsigned short* g, unsigned short* l)
{
    __builtin_amdgcn_global_load_lds(
        (const __attribute__((address_space(1))) unsigned int*)g,
        (__attribute__((address_space(3))) unsigned int*)l, 16, 0, 0);
}

// ---------------- CSR build ----------------
__global__ __launch_bounds__(256)
void count_edges_k(const int* __restrict__ ei, int* __restrict__ cnt)
{
    int e = blockIdx.x * 256 + threadIdx.x;
    if (e >= EP) return;
    int d = (e < EE) ? ei[EE + e] : (e - EE);
    atomicAdd(&cnt[d], 1);
}

__global__ __launch_bounds__(1024)
void scan_k(const int* __restrict__ cnt, int* __restrict__ row_ptr)
{
    __shared__ int sm[1024];
    int t = threadIdx.x;
    int i0 = t * 10, i1 = min(i0 + 10, NN);
    int part = 0;
    for (int i = i0; i < i1; ++i) part += cnt[i];
    sm[t] = part;
    __syncthreads();
    for (int off = 1; off < 1024; off <<= 1) {
        int v = (t >= off) ? sm[t - off] : 0;
        __syncthreads();
        sm[t] += v;
        __syncthreads();
    }
    int run = sm[t] - part;             // exclusive prefix
    for (int i = i0; i < i1; ++i) { row_ptr[i] = run; run += cnt[i]; }
    if (t == 1023) row_ptr[NN] = run;
}

__global__ __launch_bounds__(256)
void fill_csr_k(const int* __restrict__ ei, const int* __restrict__ row_ptr,
                int* __restrict__ cursor, int* __restrict__ csr)
{
    int e = blockIdx.x * 256 + threadIdx.x;
    if (e >= EP) return;
    int s, d;
    if (e < EE) { s = ei[e]; d = ei[EE + e]; } else { s = e - EE; d = s; }
    int pos = row_ptr[d] + atomicAdd(&cursor[d], 1);
    csr[pos] = s;
}

// ---------------- hi/lo bf16 conversion of x + all weights (swizzled layout) ----------------
#define C_X   2560000
#define C_EW  (C_X + 32768)
#define C_FW  (C_EW + 131072)      // gat_w (65536) + res_w (65536) -> fw rows 0..1023
#define C_DW  (C_FW + 5120)

__global__ __launch_bounds__(256)
void cvt_all_k(const float* __restrict__ x, const float* __restrict__ enc_w,
               const float* __restrict__ gat_w, const float* __restrict__ res_w,
               const float* __restrict__ dec_w,
               unsigned short* __restrict__ xhi, unsigned short* __restrict__ xlo,
               unsigned short* __restrict__ ewhi, unsigned short* __restrict__ ewlo,
               unsigned short* __restrict__ fwhi, unsigned short* __restrict__ fwlo,
               unsigned short* __restrict__ dwhi, unsigned short* __restrict__ dwlo)
{
    int iu = blockIdx.x * 256 + threadIdx.x;    // 8-element unit index
    int i = iu * 8;
    if (i >= C_DW) return;
    const float* src = nullptr; unsigned short *ph, *pl; int j, row, c, Kd;
    if (i < C_X)       { j = i;        src = x;     ph = xhi;  pl = xlo;
                         row = j >> 8; c = j & 255; Kd = 256; }
    else if (i < C_EW) { j = i - C_X;  src = enc_w; ph = ewhi; pl = ewlo;
                         row = j >> 8; c = j & 255; Kd = 256; }
    else if (i < C_FW) { j = i - C_EW; ph = fwhi;   pl = fwlo;
                         row = j >> 7; c = j & 127; Kd = 128; }
    else               { j = i - C_FW; src = dec_w; ph = dwhi; pl = dwlo;
                         row = j >> 7; c = j & 127; Kd = 128; }

    float4 v0, v1;
    if (src) { v0 = *(const float4*)(src + j); v1 = *(const float4*)(src + j + 4); }
    else {
        const float* s2 = (j < 65536) ? (gat_w + j) : (res_w + j - 65536);
        v0 = *(const float4*)s2; v1 = *(const float4*)(s2 + 4);
    }
    float vv[8] = {v0.x, v0.y, v0.z, v0.w, v1.x, v1.y, v1.z, v1.w};
    unsigned short hs[8], ls[8];
#pragma unroll
    for (int k = 0; k < 8; ++k) {
        hs[k] = f2bf(vv[k]);
        ls[k] = f2bf(vv[k] - bf2f(hs[k]));
    }
    int out = row * Kd + swz(row, c);   // c multiple of 8 -> 8 contiguous elements
    *(u16x8*)(ph + out) = *(u16x8*)hs;
    *(u16x8*)(pl + out) = *(u16x8*)ls;
}

// ---------------- fused attention weight rows: fw rows 1024..1031 (+ zero tail) ----------------
__global__ __launch_bounds__(256)
void attw_k(const float* __restrict__ gat_w, const float* __restrict__ att_src,
            const float* __restrict__ att_dst,
            unsigned short* __restrict__ fwhi, unsigned short* __restrict__ fwlo)
{
    __shared__ float sm[256];
    int b = blockIdx.x;                 // 0..7
    int is_dst = b >> 2, h = b & 3;
    const float* att = is_dst ? att_dst : att_src;
    int t = threadIdx.x;
    int k = t & 127, half = t >> 7;     // half-range of c per 128-thread group
    float s = 0.0f;
#pragma unroll 4
    for (int c = half * 64; c < half * 64 + 64; ++c)
        s = fmaf(gat_w[(size_t)(h * 128 + c) * 128 + k], att[h * 128 + c], s);
    sm[t] = s;
    __syncthreads();
    if (t < 128) {
        float v = sm[t] + sm[t + 128];
        int R = 1024 + is_dst * 4 + h;
        size_t o = (size_t)R * 128 + swz(R, k);
        unsigned short hi = f2bf(v);
        fwhi[o] = hi;
        fwlo[o] = f2bf(v - bf2f(hi));
    }
    for (int i = b * 896 + t; i < (b + 1) * 896; i += 256) {
        fwhi[1032 * 128 + i] = 0;
        fwlo[1032 * 128 + i] = 0;
    }
}

// ---------------- bf16x3 MFMA GEMM via global_load_lds staging, LDS-staged epilogue ---------
// Block 64x64, 4 waves 2x2, wave 32x32 = 2x2 MFMA tiles. acc += Ah*Wh + Ah*Wl + Al*Wh.
// Epilogue: acc -> LDS (reusing staging buffer) -> coalesced wide stores (round-7 version
// issued 16-32 scattered 2B stores/thread: store-issue-bound).
// MODE 0: dec  -> outF[row*40+col]+dec_b, cols masked < 40 (scalar path, tiny)
// MODE 1: enc  -> relu(v+enc_b) -> hi/lo bf16 (swizzled) to outH/outL, ld=128
// MODE 2: layer-> bn<512: bf16 xh (natural); 512..1023: fp32 res (+res_b); 1024+: a_src/a_dst
template<int MODE, int KTILES>
__global__ __launch_bounds__(256)
void gemm3_k(const unsigned short* __restrict__ Ahi, const unsigned short* __restrict__ Alo,
             const unsigned short* __restrict__ Bhi, const unsigned short* __restrict__ Blo,
             const float* __restrict__ bias,
             float* __restrict__ outF, unsigned short* __restrict__ outH,
             unsigned short* __restrict__ outL,
             float* __restrict__ a_src, float* __restrict__ a_dst, int M)
{
    constexpr int K = KTILES * 128;
    __shared__ __align__(16) unsigned short smem[4 * 64 * 128];   // 64 KB
    unsigned short* sAh = smem;
    unsigned short* sAl = smem + 8192;
    unsigned short* sBh = smem + 16384;
    unsigned short* sBl = smem + 24576;

    const int tid = threadIdx.x;
    const int lane = tid & 63, wv = tid >> 6;
    const int wr = (wv >> 1) * 32, wc = (wv & 1) * 32;
    const int bm = blockIdx.x * 64, bn = blockIdx.y * 64;
    const int r16 = lane & 15, q4 = lane >> 4;

    f4 acc[2][2];
#pragma unroll
    for (int i = 0; i < 2; ++i)
#pragma unroll
        for (int j = 0; j < 2; ++j) acc[i][j] = (f4){0.f, 0.f, 0.f, 0.f};

    const int ra0 = wr + r16;        // ((ra0&7)==((ra0+16)&7))
    const int rb0 = wc + r16;

    for (int kt = 0; kt < KTILES; ++kt) {
        if (kt) __syncthreads();
#pragma unroll
        for (int j = 0; j < 4; ++j) {
            int i = tid + j * 256;                    // unit index 0..1023
            int row = i >> 4, u = i & 15;
            int arow = min(bm + row, M - 1);
            int brow = bn + row;
            size_t ga = (size_t)arow * K + kt * 128 + u * 8;
            size_t gb = (size_t)brow * K + kt * 128 + u * 8;
            int lb = (wv * 64 + j * 256) * 8;         // wave-uniform LDS base (elements)
            gl_lds16(Ahi + ga, sAh + lb);
            gl_lds16(Alo + ga, sAl + lb);
            gl_lds16(Bhi + gb, sBh + lb);
            gl_lds16(Blo + gb, sBl + lb);
        }
        __syncthreads();

#pragma unroll
        for (int ks = 0; ks < 4; ++ks) {
            int u = ks * 4 + q4;
            int oa0 = ra0 * 128 + ((u ^ (ra0 & 7)) * 8);
            int ob0 = rb0 * 128 + ((u ^ (rb0 & 7)) * 8);
            int oa1 = oa0 + 16 * 128;
            int ob1 = ob0 + 16 * 128;
            bf8 A0h = *(const bf8*)(sAh + oa0);
            bf8 A1h = *(const bf8*)(sAh + oa1);
            bf8 A0l = *(const bf8*)(sAl + oa0);
            bf8 A1l = *(const bf8*)(sAl + oa1);
            bf8 B0h = *(const bf8*)(sBh + ob0);
            bf8 B1h = *(const bf8*)(sBh + ob1);
            bf8 B0l = *(const bf8*)(sBl + ob0);
            bf8 B1l = *(const bf8*)(sBl + ob1);

            acc[0][0] = __builtin_amdgcn_mfma_f32_16x16x32_bf16(A0h, B0h, acc[0][0], 0, 0, 0);
            acc[0][1] = __builtin_amdgcn_mfma_f32_16x16x32_bf16(A0h, B1h, acc[0][1], 0, 0, 0);
            acc[1][0] = __builtin_amdgcn_mfma_f32_16x16x32_bf16(A1h, B0h, acc[1][0], 0, 0, 0);
            acc[1][1] = __builtin_amdgcn_mfma_f32_16x16x32_bf16(A1h, B1h, acc[1][1], 0, 0, 0);
            acc[0][0] = __builtin_amdgcn_mfma_f32_16x16x32_bf16(A0h, B0l, acc[0][0], 0, 0, 0);
            acc[0][1] = __builtin_amdgcn_mfma_f32_16x16x32_bf16(A0h, B1l, acc[0][1], 0, 0, 0);
            acc[1][0] = __builtin_amdgcn_mfma_f32_16x16x32_bf16(A1h, B0l, acc[1][0], 0, 0, 0);
            acc[1][1] = __builtin_amdgcn_mfma_f32_16x16x32_bf16(A1h, B1l, acc[1][1], 0, 0, 0);
            acc[0][0] = __builtin_amdgcn_mfma_f32_16x16x32_bf16(A0l, B0h, acc[0][0], 0, 0, 0);
            acc[0][1] = __builtin_amdgcn_mfma_f32_16x16x32_bf16(A0l, B1h, acc[0][1], 0, 0, 0);
            acc[1][0] = __builtin_amdgcn_mfma_f32_16x16x32_bf16(A1l, B0h, acc[1][0], 0, 0, 0);
            acc[1][1] = __builtin_amdgcn_mfma_f32_16x16x32_bf16(A1l, B1h, acc[1][1], 0, 0, 0);
        }
    }

    const int rbase = q4 * 4;

    if (MODE == 0 || (MODE == 2 && bn >= 1024)) {
        // scalar epilogue: dec (40 cols) / attn columns (8 cols) — tiny, block-uniform
#pragma unroll
        for (int i = 0; i < 2; ++i)
#pragma unroll
            for (int j = 0; j < 2; ++j)
#pragma unroll
                for (int r = 0; r < 4; ++r) {
                    int row = bm + wr + i * 16 + rbase + r;
                    int col = bn + wc + j * 16 + r16;
                    if (row >= M) continue;
                    float v = acc[i][j][r];
                    if (MODE == 0) {
                        if (col < NCLASS)
                            outF[(size_t)row * NCLASS + col] = v + bias[col];
                    } else {
                        if (col < 1032) {
                            int h = col - 1024;
                            if (h < 4) a_src[row * 4 + h] = v;
                            else       a_dst[row * 4 + h - 4] = v;
                        }
                    }
                }
        return;
    }

    // ---- staged coalesced epilogue ----
    __syncthreads();
    float* sC = (float*)smem;                 // 64 x 65 fp32 (padded stride)
#pragma unroll
    for (int i = 0; i < 2; ++i)
#pragma unroll
        for (int j = 0; j < 2; ++j)
#pragma unroll
            for (int r = 0; r < 4; ++r)
                sC[(wr + i * 16 + rbase + r) * 65 + (wc + j * 16 + r16)] = acc[i][j][r];
    __syncthreads();

    int row = tid >> 2, seg = tid & 3, c0 = seg * 16;
    int grow = bm + row;
    if (grow >= M) return;
    float v[16];
#pragma unroll
    for (int k = 0; k < 16; ++k) v[k] = sC[row * 65 + c0 + k];

    if (MODE == 1) {
        unsigned short hs[16], ls[16];
#pragma unroll
        for (int k = 0; k < 16; ++k) {
            float u = fmaxf(v[k] + bias[bn + c0 + k], 0.0f);
            hs[k] = f2bf(u);
            ls[k] = f2bf(u - bf2f(hs[k]));
        }
#pragma unroll
        for (int uu = 0; uu < 2; ++uu) {
            int ug = (bn + c0) / 8 + uu;
            int pu = ug ^ (grow & 7);
            *(u16x8*)(outH + (size_t)grow * 128 + pu * 8) = *(u16x8*)(hs + uu * 8);
            *(u16x8*)(outL + (size_t)grow * 128 + pu * 8) = *(u16x8*)(ls + uu * 8);
        }
    } else {                                  // MODE 2, bn < 1024
        if (bn < 512) {
            unsigned short hs[16];
#pragma unroll
            for (int k = 0; k < 16; ++k) hs[k] = f2bf(v[k]);
            *(u16x8*)(outH + (size_t)grow * 512 + bn + c0)     = *(u16x8*)hs;
            *(u16x8*)(outH + (size_t)grow * 512 + bn + c0 + 8) = *(u16x8*)(hs + 8);
        } else {
#pragma unroll
            for (int k = 0; k < 16; ++k) v[k] += bias[bn - 512 + c0 + k];
            float* dst = outF + (size_t)grow * 512 + (bn - 512) + c0;
#pragma unroll
            for (int k4 = 0; k4 < 4; ++k4)
                *(float4*)(dst + k4 * 4) =
                    make_float4(v[k4 * 4], v[k4 * 4 + 1], v[k4 * 4 + 2], v[k4 * 4 + 3]);
        }
    }
}

// ------- fused softmax + gather + residual + ELU + head-mean -> X (hi/lo bf16, swizzled) ----
// alpha_k folded in: each lane computes w=exp(leaky(a_src+a_dst)) for its own head on the
// fly and accumulates its complete ssum (loop is lane-uniform over the node's edges).
__global__ __launch_bounds__(256)
void agg_k(const int* __restrict__ row_ptr, const int* __restrict__ csr,
           const float* __restrict__ a_src, const float* __restrict__ a_dst,
           const unsigned short* __restrict__ xh_b, const float* __restrict__ res,
           const float* __restrict__ gat_b,
           unsigned short* __restrict__ Xhi, unsigned short* __restrict__ Xlo)
{
    int wave = threadIdx.x >> 6, lane = threadIdx.x & 63;
    int d = blockIdx.x * 4 + wave;
    if (d >= NN) return;
    int beg = row_ptr[d], end = row_ptr[d + 1];
    int hl = lane >> 4;                       // head owned by this lane's cols
    int cb = lane * 8;                        // 8 bf16 cols = 16 B per lane
    float ad = a_dst[d * 4 + hl];

    float acc[8];
#pragma unroll
    for (int k = 0; k < 8; ++k) acc[k] = 0.0f;
    float ssum = 0.0f;

    int e = beg;
    for (; e + 8 <= end; e += 8) {            // 8 gathers in flight per wave
        int sv[8]; float w[8]; u16x8 v[8];
#pragma unroll
        for (int q = 0; q < 8; ++q) sv[q] = csr[e + q];
#pragma unroll
        for (int q = 0; q < 8; ++q) v[q] = *(const u16x8*)(xh_b + (size_t)sv[q] * HF + cb);
#pragma unroll
        for (int q = 0; q < 8; ++q) {
            w[q] = __expf(leaky02(a_src[sv[q] * 4 + hl] + ad));
            ssum += w[q];
        }
#pragma unroll
        for (int q = 0; q < 8; ++q)
#pragma unroll
            for (int k = 0; k < 8; ++k) acc[k] = fmaf(w[q], bf2f(v[q][k]), acc[k]);
    }
    for (; e + 4 <= end; e += 4) {
        int sv[4]; float w[4]; u16x8 v[4];
#pragma unroll
        for (int q = 0; q < 4; ++q) sv[q] = csr[e + q];
#pragma unroll
        for (int q = 0; q < 4; ++q) v[q] = *(const u16x8*)(xh_b + (size_t)sv[q] * HF + cb);
#pragma unroll
        for (int q = 0; q < 4; ++q) {
            w[q] = __expf(leaky02(a_src[sv[q] * 4 + hl] + ad));
            ssum += w[q];
        }
#pragma unroll
        for (int q = 0; q < 4; ++q)
#pragma unroll
            for (int k = 0; k < 8; ++k) acc[k] = fmaf(w[q], bf2f(v[q][k]), acc[k]);
    }
    for (; e < end; ++e) {
        int s = csr[e];
        float w = __expf(leaky02(a_src[s * 4 + hl] + ad));
        ssum += w;
        u16x8 v = *(const u16x8*)(xh_b + (size_t)s * HF + cb);
#pragma unroll
        for (int k = 0; k < 8; ++k) acc[k] = fmaf(w, bf2f(v[k]), acc[k]);
    }

    float inv = 1.0f / ssum;
    const float* rr = res + (size_t)d * HF + cb;
    const float* gb = gat_b + cb;
    float u[8];
#pragma unroll
    for (int k = 0; k < 8; ++k) {
        float v = fmaf(acc[k], inv, gb[k] + rr[k]);
        u[k] = (v > 0.0f) ? v : expm1f(v);
    }
    float z0 = (u[0] + u[1] + u[2] + u[3]) * 0.25f;
    float z1 = (u[4] + u[5] + u[6] + u[7]) * 0.25f;
    unsigned short h0 = f2bf(z0), h1 = f2bf(z1);
    unsigned short l0 = f2bf(z0 - bf2f(h0)), l1 = f2bf(z1 - bf2f(h1));
    int pos = swz(d, lane * 2);               // 2 consecutive cols stay in one unit
    size_t idx = (size_t)d * NHID + pos;
    *(unsigned*)(Xhi + idx) = ((unsigned)h1 << 16) | h0;
    *(unsigned*)(Xlo + idx) = ((unsigned)l1 << 16) | l0;
}

// ---------------- launcher ----------------
extern "C" void kernel_launch(void* const* d_in, const int* in_sizes, int n_in,
                              void* d_out, int out_size, void* d_ws, size_t ws_size,
                              hipStream_t stream)
{
    const float* x       = (const float*)d_in[0];
    const int*   ei      = (const int*)d_in[1];
    const float* enc_w   = (const float*)d_in[2];
    const float* enc_b   = (const float*)d_in[3];
    const float* res_w   = (const float*)d_in[4];
    const float* res_b   = (const float*)d_in[5];
    const float* gat_w   = (const float*)d_in[6];
    const float* att_src = (const float*)d_in[7];
    const float* att_dst = (const float*)d_in[8];
    const float* gat_b   = (const float*)d_in[9];
    const float* dec_w   = (const float*)d_in[10];
    const float* dec_b   = (const float*)d_in[11];
    float* out = (float*)d_out;

    char* p = (char*)d_ws;
    auto alloc = [&](size_t bytes) -> void* {
        void* r = (void*)p;
        p += (bytes + 255) & ~(size_t)255;
        return r;
    };
    float* res    = (float*)alloc(5120000 * 4);            // [N,512] fp32
    float* a_src  = (float*)alloc(40000 * 4);
    float* a_dst  = (float*)alloc(40000 * 4);
    unsigned short* xh_b = (unsigned short*)alloc(5120000 * 2);     // [N,512] bf16 (natural)
    unsigned short* Xhi  = (unsigned short*)alloc(1280000 * 2);     // [N,128] bf16 (swizzled)
    unsigned short* Xlo  = (unsigned short*)alloc(1280000 * 2);
    unsigned short* xhi  = (unsigned short*)alloc(2560000 * 2);     // x hi/lo [N,256] (swizzled)
    unsigned short* xlo  = (unsigned short*)alloc(2560000 * 2);
    unsigned short* ewhi = (unsigned short*)alloc(32768 * 2);       // enc_w [128,256] (swizzled)
    unsigned short* ewlo = (unsigned short*)alloc(32768 * 2);
    unsigned short* fwhi = (unsigned short*)alloc(FCOLS * 128 * 2); // [1088,128] (swizzled)
    unsigned short* fwlo = (unsigned short*)alloc(FCOLS * 128 * 2);
    int* row_ptr = (int*)alloc(10004 * 4);
    int* csr     = (int*)alloc(170000 * 4);
    // ---- zero zone (single memset): padded dec W + cnt + cursor ----
    char* zbase = p;
    unsigned short* dwhi = (unsigned short*)alloc(8192 * 2);        // [64,128] padded (swizzled)
    unsigned short* dwlo = (unsigned short*)alloc(8192 * 2);
    int* cnt    = (int*)alloc(10000 * 4);
    int* cursor = (int*)alloc(10000 * 4);
    size_t zbytes = (size_t)(p - zbase);

    hipMemsetAsync(zbase, 0, zbytes, stream);

    // CSR build (graph static across both layers)
    int eb = (EP + 255) / 256;
    count_edges_k<<<eb, 256, 0, stream>>>(ei, cnt);
    scan_k<<<1, 1024, 0, stream>>>(cnt, row_ptr);
    fill_csr_k<<<eb, 256, 0, stream>>>(ei, row_ptr, cursor, csr);

    // hi/lo conversions (x + all weights), 8 elems/thread, swizzled stores
    cvt_all_k<<<(C_DW / 8 + 255) / 256, 256, 0, stream>>>(
        x, enc_w, gat_w, res_w, dec_w,
        xhi, xlo, ewhi, ewlo, fwhi, fwlo, dwhi, dwlo);
    // fused attention weight rows (fw rows 1024..1031 + zero tail), 8 coalesced blocks
    attw_k<<<8, 256, 0, stream>>>(gat_w, att_src, att_dst, fwhi, fwlo);

    // encoder: X = relu(x @ enc_w.T + enc_b) -> hi/lo bf16  (K=256 -> 2 K-tiles)
    gemm3_k<1, 2><<<dim3(157, 2), 256, 0, stream>>>(
        xhi, xlo, ewhi, ewlo, enc_b, nullptr, Xhi, Xlo, nullptr, nullptr, NN);

    for (int layer = 0; layer < 2; ++layer) {
        // fused [xh | res | a_src a_dst] = X @ [gat_w; res_w; As; Ad].T
        gemm3_k<2, 1><<<dim3(157, 17), 256, 0, stream>>>(
            Xhi, Xlo, fwhi, fwlo, res_b, res, xh_b, nullptr, a_src, a_dst, NN);
        // softmax+aggregate+residual+ELU+head-mean (alpha fused in)
        agg_k<<<2500, 256, 0, stream>>>(row_ptr, csr, a_src, a_dst, xh_b, res, gat_b, Xhi, Xlo);
    }

    // decoder: out = X @ dec_w.T + dec_b
    gemm3_k<0, 1><<<dim3(157, 1), 256, 0, stream>>>(
        Xhi, Xlo, dwhi, dwlo, dec_b, out, nullptr, nullptr, nullptr, nullptr, NN);
}

// Round 9
// 225.173 us; speedup vs baseline: 1.5650x; 1.1230x over previous
//
#include <hip/hip_runtime.h>
#include <math.h>

#define NN 10000
#define EE 160000
#define EP 170000          // EE + NN self loops
#define NFEAT 256
#define NHID 128
#define NH 4
#define HF 512             // NH * NHID
#define NCLASS 40
#define FCOLS 1088         // 512 xh + 512 res + 8 attn + 56 pad

typedef __attribute__((ext_vector_type(8))) short bf8;     // 8 bf16 (4 VGPR) MFMA frag
typedef __attribute__((ext_vector_type(8))) unsigned short u16x8;
typedef __attribute__((ext_vector_type(4))) float f4;

__device__ __forceinline__ float leaky02(float x) { return x >= 0.0f ? x : 0.2f * x; }

__device__ __forceinline__ unsigned short f2bf(float f) {   // RNE
    unsigned u = __builtin_bit_cast(unsigned, f);
    unsigned r = (u + 0x7FFF + ((u >> 16) & 1)) >> 16;
    return (unsigned short)r;
}
__device__ __forceinline__ float bf2f(unsigned short h) {
    return __builtin_bit_cast(float, (unsigned)h << 16);
}

// Bank-swizzled element position within a row of length K (baked into GLOBAL layout
// of MFMA operands so global->LDS staging is a LINEAR copy for global_load_lds).
__device__ __forceinline__ int swz(int row, int c) {
    return ((((c >> 3) ^ (row & 7)) << 3) | (c & 7));
}

// 16B global -> LDS direct DMA
__device__ __forceinline__ void gl_lds16(const unsigned short* g, unsigned short* l)
{
    __builtin_amdgcn_global_load_lds(
        (const __attribute__((address_space(1))) unsigned int*)g,
        (__attribute__((address_space(3))) unsigned int*)l, 16, 0, 0);
}

// ---------------- fused setup: cvt (hi/lo, swizzled) + attw + biasRG + edge count ----------
#define C_X   2560000
#define C_EW  (C_X + 32768)
#define C_FW  (C_EW + 131072)      // gat_w + res_w -> fw rows 0..1023
#define C_DW  (C_FW + 5120)
#define CVT_B  1333                // ceil((C_DW/8)/256)
#define ATTW_B (CVT_B + 8)
#define TOT_B  (ATTW_B + 166)

__global__ __launch_bounds__(256)
void fused0_k(const float* __restrict__ x, const float* __restrict__ enc_w,
              const float* __restrict__ gat_w, const float* __restrict__ res_w,
              const float* __restrict__ dec_w, const float* __restrict__ att_src,
              const float* __restrict__ att_dst, const float* __restrict__ res_b,
              const float* __restrict__ gat_b, const int* __restrict__ ei,
              unsigned short* __restrict__ xhi, unsigned short* __restrict__ xlo,
              unsigned short* __restrict__ ewhi, unsigned short* __restrict__ ewlo,
              unsigned short* __restrict__ fwhi, unsigned short* __restrict__ fwlo,
              unsigned short* __restrict__ dwhi, unsigned short* __restrict__ dwlo,
              float* __restrict__ biasRG, int* __restrict__ cnt)
{
    int bId = blockIdx.x;
    int t = threadIdx.x;
    if (bId < CVT_B) {
        // ---- hi/lo conversion, swizzled layout ----
        int iu = bId * 256 + t;
        int i = iu * 8;
        if (i >= C_DW) return;
        const float* src = nullptr; unsigned short *ph, *pl; int j, row, c, Kd;
        if (i < C_X)       { j = i;        src = x;     ph = xhi;  pl = xlo;
                             row = j >> 8; c = j & 255; Kd = 256; }
        else if (i < C_EW) { j = i - C_X;  src = enc_w; ph = ewhi; pl = ewlo;
                             row = j >> 8; c = j & 255; Kd = 256; }
        else if (i < C_FW) { j = i - C_EW; ph = fwhi;   pl = fwlo;
                             row = j >> 7; c = j & 127; Kd = 128; }
        else               { j = i - C_FW; src = dec_w; ph = dwhi; pl = dwlo;
                             row = j >> 7; c = j & 127; Kd = 128; }
        float4 v0, v1;
        if (src) { v0 = *(const float4*)(src + j); v1 = *(const float4*)(src + j + 4); }
        else {
            const float* s2 = (j < 65536) ? (gat_w + j) : (res_w + j - 65536);
            v0 = *(const float4*)s2; v1 = *(const float4*)(s2 + 4);
        }
        float vv[8] = {v0.x, v0.y, v0.z, v0.w, v1.x, v1.y, v1.z, v1.w};
        unsigned short hs[8], ls[8];
#pragma unroll
        for (int k = 0; k < 8; ++k) {
            hs[k] = f2bf(vv[k]);
            ls[k] = f2bf(vv[k] - bf2f(hs[k]));
        }
        int outp = row * Kd + swz(row, c);
        *(u16x8*)(ph + outp) = *(u16x8*)hs;
        *(u16x8*)(pl + outp) = *(u16x8*)ls;
    } else if (bId < ATTW_B) {
        // ---- attention weight rows (fw 1024..1031) + zero tail + biasRG ----
        __shared__ float sm[256];
        int b = bId - CVT_B;            // 0..7
        int is_dst = b >> 2, h = b & 3;
        const float* att = is_dst ? att_dst : att_src;
        int k = t & 127, half = t >> 7;
        float s = 0.0f;
#pragma unroll 4
        for (int c = half * 64; c < half * 64 + 64; ++c)
            s = fmaf(gat_w[(size_t)(h * 128 + c) * 128 + k], att[h * 128 + c], s);
        sm[t] = s;
        __syncthreads();
        if (t < 128) {
            float v = sm[t] + sm[t + 128];
            int R = 1024 + is_dst * 4 + h;
            size_t o = (size_t)R * 128 + swz(R, k);
            unsigned short hi = f2bf(v);
            fwhi[o] = hi;
            fwlo[o] = f2bf(v - bf2f(hi));
        }
        for (int i = b * 896 + t; i < (b + 1) * 896; i += 256) {
            fwhi[1032 * 128 + i] = 0;
            fwlo[1032 * 128 + i] = 0;
        }
        if (b < 2) {                    // biasRG = res_b + gat_b (512 elems over 2 blocks)
            int c = b * 256 + t;
            biasRG[c] = res_b[c] + gat_b[c];
        }
    } else {
        // ---- edge count (grid-stride) ----
        for (int e = (bId - ATTW_B) * 256 + t; e < EP; e += (TOT_B - ATTW_B) * 256) {
            int d = (e < EE) ? ei[EE + e] : (e - EE);
            atomicAdd(&cnt[d], 1);
        }
    }
}

// ---------------- bf16x3 MFMA GEMM + LDS-staged epilogue + optional merged tail slice ------
// MODE 0: dec  -> outF[row*40+col]+bias
// MODE 1: enc  -> relu(v+bias) -> hi/lo bf16 (swizzled), ld=128
// MODE 2: layer-> bn<512: bf16 xh (natural, outH); 512..1023: bf16 res+biasRG (outL);
//                 1024..1031: a_src/a_dst fp32
// MERGE 1: last y-slice, x==0 runs the CSR prefix scan (cnt -> row_ptr)
// MERGE 2: last y-slice runs grid-stride fill_csr
template<int MODE, int KTILES, int MERGE>
__global__ __launch_bounds__(256)
void gemm3_k(const unsigned short* __restrict__ Ahi, const unsigned short* __restrict__ Alo,
             const unsigned short* __restrict__ Bhi, const unsigned short* __restrict__ Blo,
             const float* __restrict__ bias,
             float* __restrict__ outF, unsigned short* __restrict__ outH,
             unsigned short* __restrict__ outL,
             float* __restrict__ a_src, float* __restrict__ a_dst, int M,
             const int* __restrict__ ei, const int* __restrict__ cnt,
             int* __restrict__ row_ptr, int* __restrict__ cursor, int* __restrict__ csr)
{
    constexpr int K = KTILES * 128;
    __shared__ __align__(16) unsigned short smem[4 * 64 * 128];   // 64 KB
    const int tid = threadIdx.x;

    if (MERGE && blockIdx.y == gridDim.y - 1) {
        if (MERGE == 1) {
            if (blockIdx.x != 0) return;
            int* smi = (int*)smem;
            int i0 = tid * 40, i1 = min(i0 + 40, NN);
            int part = 0;
            for (int i = i0; i < i1; ++i) part += cnt[i];
            smi[tid] = part;
            __syncthreads();
            for (int off = 1; off < 256; off <<= 1) {
                int v = (tid >= off) ? smi[tid - off] : 0;
                __syncthreads();
                smi[tid] += v;
                __syncthreads();
            }
            int run = smi[tid] - part;
            for (int i = i0; i < i1; ++i) { row_ptr[i] = run; run += cnt[i]; }
            if (tid == 255) row_ptr[NN] = run;
        } else {
            int stride = gridDim.x * 256;
            for (int e = blockIdx.x * 256 + tid; e < EP; e += stride) {
                int s, d;
                if (e < EE) { s = ei[e]; d = ei[EE + e]; } else { s = e - EE; d = s; }
                int pos = row_ptr[d] + atomicAdd(&cursor[d], 1);
                csr[pos] = s;
            }
        }
        return;
    }

    unsigned short* sAh = smem;
    unsigned short* sAl = smem + 8192;
    unsigned short* sBh = smem + 16384;
    unsigned short* sBl = smem + 24576;

    const int lane = tid & 63, wv = tid >> 6;
    const int wr = (wv >> 1) * 32, wc = (wv & 1) * 32;
    const int bm = blockIdx.x * 64, bn = blockIdx.y * 64;
    const int r16 = lane & 15, q4 = lane >> 4;

    f4 acc[2][2];
#pragma unroll
    for (int i = 0; i < 2; ++i)
#pragma unroll
        for (int j = 0; j < 2; ++j) acc[i][j] = (f4){0.f, 0.f, 0.f, 0.f};

    const int ra0 = wr + r16;
    const int rb0 = wc + r16;

    for (int kt = 0; kt < KTILES; ++kt) {
        if (kt) __syncthreads();
#pragma unroll
        for (int j = 0; j < 4; ++j) {
            int i = tid + j * 256;                    // unit index 0..1023
            int row = i >> 4, u = i & 15;
            int arow = min(bm + row, M - 1);
            int brow = bn + row;
            size_t ga = (size_t)arow * K + kt * 128 + u * 8;
            size_t gb = (size_t)brow * K + kt * 128 + u * 8;
            int lb = (wv * 64 + j * 256) * 8;         // wave-uniform LDS base
            gl_lds16(Ahi + ga, sAh + lb);
            gl_lds16(Alo + ga, sAl + lb);
            gl_lds16(Bhi + gb, sBh + lb);
            gl_lds16(Blo + gb, sBl + lb);
        }
        __syncthreads();

#pragma unroll
        for (int ks = 0; ks < 4; ++ks) {
            int u = ks * 4 + q4;
            int oa0 = ra0 * 128 + ((u ^ (ra0 & 7)) * 8);
            int ob0 = rb0 * 128 + ((u ^ (rb0 & 7)) * 8);
            int oa1 = oa0 + 16 * 128;
            int ob1 = ob0 + 16 * 128;
            bf8 A0h = *(const bf8*)(sAh + oa0);
            bf8 A1h = *(const bf8*)(sAh + oa1);
            bf8 A0l = *(const bf8*)(sAl + oa0);
            bf8 A1l = *(const bf8*)(sAl + oa1);
            bf8 B0h = *(const bf8*)(sBh + ob0);
            bf8 B1h = *(const bf8*)(sBh + ob1);
            bf8 B0l = *(const bf8*)(sBl + ob0);
            bf8 B1l = *(const bf8*)(sBl + ob1);

            acc[0][0] = __builtin_amdgcn_mfma_f32_16x16x32_bf16(A0h, B0h, acc[0][0], 0, 0, 0);
            acc[0][1] = __builtin_amdgcn_mfma_f32_16x16x32_bf16(A0h, B1h, acc[0][1], 0, 0, 0);
            acc[1][0] = __builtin_amdgcn_mfma_f32_16x16x32_bf16(A1h, B0h, acc[1][0], 0, 0, 0);
            acc[1][1] = __builtin_amdgcn_mfma_f32_16x16x32_bf16(A1h, B1h, acc[1][1], 0, 0, 0);
            acc[0][0] = __builtin_amdgcn_mfma_f32_16x16x32_bf16(A0h, B0l, acc[0][0], 0, 0, 0);
            acc[0][1] = __builtin_amdgcn_mfma_f32_16x16x32_bf16(A0h, B1l, acc[0][1], 0, 0, 0);
            acc[1][0] = __builtin_amdgcn_mfma_f32_16x16x32_bf16(A1h, B0l, acc[1][0], 0, 0, 0);
            acc[1][1] = __builtin_amdgcn_mfma_f32_16x16x32_bf16(A1h, B1l, acc[1][1], 0, 0, 0);
            acc[0][0] = __builtin_amdgcn_mfma_f32_16x16x32_bf16(A0l, B0h, acc[0][0], 0, 0, 0);
            acc[0][1] = __builtin_amdgcn_mfma_f32_16x16x32_bf16(A0l, B1h, acc[0][1], 0, 0, 0);
            acc[1][0] = __builtin_amdgcn_mfma_f32_16x16x32_bf16(A1l, B0h, acc[1][0], 0, 0, 0);
            acc[1][1] = __builtin_amdgcn_mfma_f32_16x16x32_bf16(A1l, B1h, acc[1][1], 0, 0, 0);
        }
    }

    const int rbase = q4 * 4;

    if (MODE == 0 || (MODE == 2 && bn >= 1024)) {
        // scalar epilogue: dec (40 cols) / attn columns (8 cols)
#pragma unroll
        for (int i = 0; i < 2; ++i)
#pragma unroll
            for (int j = 0; j < 2; ++j)
#pragma unroll
                for (int r = 0; r < 4; ++r) {
                    int row = bm + wr + i * 16 + rbase + r;
                    int col = bn + wc + j * 16 + r16;
                    if (row >= M) continue;
                    float v = acc[i][j][r];
                    if (MODE == 0) {
                        if (col < NCLASS)
                            outF[(size_t)row * NCLASS + col] = v + bias[col];
                    } else {
                        if (col < 1032) {
                            int h = col - 1024;
                            if (h < 4) a_src[row * 4 + h] = v;
                            else       a_dst[row * 4 + h - 4] = v;
                        }
                    }
                }
        return;
    }

    // ---- staged coalesced epilogue ----
    __syncthreads();
    float* sC = (float*)smem;                 // 64 x 65 fp32 (padded stride)
#pragma unroll
    for (int i = 0; i < 2; ++i)
#pragma unroll
        for (int j = 0; j < 2; ++j)
#pragma unroll
            for (int r = 0; r < 4; ++r)
                sC[(wr + i * 16 + rbase + r) * 65 + (wc + j * 16 + r16)] = acc[i][j][r];
    __syncthreads();

    int row = tid >> 2, seg = tid & 3, c0 = seg * 16;
    int grow = bm + row;
    if (grow >= M) return;
    float v[16];
#pragma unroll
    for (int k = 0; k < 16; ++k) v[k] = sC[row * 65 + c0 + k];

    if (MODE == 1) {
        unsigned short hs[16], ls[16];
#pragma unroll
        for (int k = 0; k < 16; ++k) {
            float u = fmaxf(v[k] + bias[bn + c0 + k], 0.0f);
            hs[k] = f2bf(u);
            ls[k] = f2bf(u - bf2f(hs[k]));
        }
#pragma unroll
        for (int uu = 0; uu < 2; ++uu) {
            int ug = (bn + c0) / 8 + uu;
            int pu = ug ^ (grow & 7);
            *(u16x8*)(outH + (size_t)grow * 128 + pu * 8) = *(u16x8*)(hs + uu * 8);
            *(u16x8*)(outL + (size_t)grow * 128 + pu * 8) = *(u16x8*)(ls + uu * 8);
        }
    } else {                                  // MODE 2, bn < 1024
        if (bn < 512) {                       // xh -> bf16 (natural), outH
            unsigned short hs[16];
#pragma unroll
            for (int k = 0; k < 16; ++k) hs[k] = f2bf(v[k]);
            *(u16x8*)(outH + (size_t)grow * 512 + bn + c0)     = *(u16x8*)hs;
            *(u16x8*)(outH + (size_t)grow * 512 + bn + c0 + 8) = *(u16x8*)(hs + 8);
        } else {                              // res+res_b+gat_b -> bf16 (natural), outL
            unsigned short hs[16];
#pragma unroll
            for (int k = 0; k < 16; ++k) hs[k] = f2bf(v[k] + bias[bn - 512 + c0 + k]);
            *(u16x8*)(outL + (size_t)grow * 512 + (bn - 512) + c0)     = *(u16x8*)hs;
            *(u16x8*)(outL + (size_t)grow * 512 + (bn - 512) + c0 + 8) = *(u16x8*)(hs + 8);
        }
    }
}

// ------- fused softmax + gather + residual + ELU + head-mean -> X (hi/lo bf16, swizzled) ----
// Two half-waves per node (2 nodes per 256-block): each half aggregates half the edge list
// (own ssum partial); partials combined through LDS. Doubles memory parallelism and halves
// the high-degree tail vs one-wave-per-node.
__global__ __launch_bounds__(256)
void agg_k(const int* __restrict__ row_ptr, const int* __restrict__ csr,
           const float* __restrict__ a_src, const float* __restrict__ a_dst,
           const unsigned short* __restrict__ xh_b, const unsigned short* __restrict__ resb,
           unsigned short* __restrict__ Xhi, unsigned short* __restrict__ Xlo)
{
    __shared__ float sAcc[2][64][8];
    __shared__ float sSum[2][64];
    int wv = threadIdx.x >> 6, lane = threadIdx.x & 63;
    int pair = wv >> 1, half = wv & 1;
    int d = blockIdx.x * 2 + pair;            // NN=10000, grid 5000: exact
    int beg = row_ptr[d], end = row_ptr[d + 1];
    int len = end - beg;
    int h0 = (len + 1) >> 1;
    int eb = half ? (beg + h0) : beg;
    int en = half ? end : (beg + h0);
    int hl = lane >> 4;                       // head owned by this lane's cols
    int cb = lane * 8;
    float ad = a_dst[d * 4 + hl];
    // residual row (bf16, gat_b+res_b already folded in) — issue early
    u16x8 rv = *(const u16x8*)(resb + (size_t)d * HF + cb);

    float acc[8];
#pragma unroll
    for (int k = 0; k < 8; ++k) acc[k] = 0.0f;
    float ssum = 0.0f;

    int e = eb;
    for (; e + 8 <= en; e += 8) {
        int sv[8]; float w[8]; u16x8 v[8];
#pragma unroll
        for (int q = 0; q < 8; ++q) sv[q] = csr[e + q];
#pragma unroll
        for (int q = 0; q < 8; ++q) v[q] = *(const u16x8*)(xh_b + (size_t)sv[q] * HF + cb);
#pragma unroll
        for (int q = 0; q < 8; ++q) {
            w[q] = __expf(leaky02(a_src[sv[q] * 4 + hl] + ad));
            ssum += w[q];
        }
#pragma unroll
        for (int q = 0; q < 8; ++q)
#pragma unroll
            for (int k = 0; k < 8; ++k) acc[k] = fmaf(w[q], bf2f(v[q][k]), acc[k]);
    }
    for (; e + 4 <= en; e += 4) {
        int sv[4]; float w[4]; u16x8 v[4];
#pragma unroll
        for (int q = 0; q < 4; ++q) sv[q] = csr[e + q];
#pragma unroll
        for (int q = 0; q < 4; ++q) v[q] = *(const u16x8*)(xh_b + (size_t)sv[q] * HF + cb);
#pragma unroll
        for (int q = 0; q < 4; ++q) {
            w[q] = __expf(leaky02(a_src[sv[q] * 4 + hl] + ad));
            ssum += w[q];
        }
#pragma unroll
        for (int q = 0; q < 4; ++q)
#pragma unroll
            for (int k = 0; k < 8; ++k) acc[k] = fmaf(w[q], bf2f(v[q][k]), acc[k]);
    }
    for (; e < en; ++e) {
        int s = csr[e];
        float w = __expf(leaky02(a_src[s * 4 + hl] + ad));
        ssum += w;
        u16x8 v = *(const u16x8*)(xh_b + (size_t)s * HF + cb);
#pragma unroll
        for (int k = 0; k < 8; ++k) acc[k] = fmaf(w, bf2f(v[k]), acc[k]);
    }

    if (half) {
        *(float4*)&sAcc[pair][lane][0] = make_float4(acc[0], acc[1], acc[2], acc[3]);
        *(float4*)&sAcc[pair][lane][4] = make_float4(acc[4], acc[5], acc[6], acc[7]);
        sSum[pair][lane] = ssum;
    }
    __syncthreads();
    if (half) return;
#pragma unroll
    for (int k = 0; k < 8; ++k) acc[k] += sAcc[pair][lane][k];
    ssum += sSum[pair][lane];

    float inv = 1.0f / ssum;
    float u[8];
#pragma unroll
    for (int k = 0; k < 8; ++k) {
        float v = fmaf(acc[k], inv, bf2f(rv[k]));
        u[k] = (v > 0.0f) ? v : expm1f(v);
    }
    float z0 = (u[0] + u[1] + u[2] + u[3]) * 0.25f;
    float z1 = (u[4] + u[5] + u[6] + u[7]) * 0.25f;
    unsigned short h0b = f2bf(z0), h1b = f2bf(z1);
    unsigned short l0b = f2bf(z0 - bf2f(h0b)), l1b = f2bf(z1 - bf2f(h1b));
    int pos = swz(d, lane * 2);
    size_t idx = (size_t)d * NHID + pos;
    *(unsigned*)(Xhi + idx) = ((unsigned)h1b << 16) | h0b;
    *(unsigned*)(Xlo + idx) = ((unsigned)l1b << 16) | l0b;
}

// ---------------- launcher ----------------
extern "C" void kernel_launch(void* const* d_in, const int* in_sizes, int n_in,
                              void* d_out, int out_size, void* d_ws, size_t ws_size,
                              hipStream_t stream)
{
    const float* x       = (const float*)d_in[0];
    const int*   ei      = (const int*)d_in[1];
    const float* enc_w   = (const float*)d_in[2];
    const float* enc_b   = (const float*)d_in[3];
    const float* res_w   = (const float*)d_in[4];
    const float* res_b   = (const float*)d_in[5];
    const float* gat_w   = (const float*)d_in[6];
    const float* att_src = (const float*)d_in[7];
    const float* att_dst = (const float*)d_in[8];
    const float* gat_b   = (const float*)d_in[9];
    const float* dec_w   = (const float*)d_in[10];
    const float* dec_b   = (const float*)d_in[11];
    float* out = (float*)d_out;

    char* p = (char*)d_ws;
    auto alloc = [&](size_t bytes) -> void* {
        void* r = (void*)p;
        p += (bytes + 255) & ~(size_t)255;
        return r;
    };
    float* a_src  = (float*)alloc(40000 * 4);
    float* a_dst  = (float*)alloc(40000 * 4);
    float* biasRG = (float*)alloc(512 * 4);
    unsigned short* xh_b = (unsigned short*)alloc(5120000 * 2);     // [N,512] bf16 (natural)
    unsigned short* resb = (unsigned short*)alloc(5120000 * 2);     // [N,512] bf16 (natural)
    unsigned short* Xhi  = (unsigned short*)alloc(1280000 * 2);     // [N,128] bf16 (swizzled)
    unsigned short* Xlo  = (unsigned short*)alloc(1280000 * 2);
    unsigned short* xhi  = (unsigned short*)alloc(2560000 * 2);     // x hi/lo [N,256] (swizzled)
    unsigned short* xlo  = (unsigned short*)alloc(2560000 * 2);
    unsigned short* ewhi = (unsigned short*)alloc(32768 * 2);       // enc_w (swizzled)
    unsigned short* ewlo = (unsigned short*)alloc(32768 * 2);
    unsigned short* fwhi = (unsigned short*)alloc(FCOLS * 128 * 2); // [1088,128] (swizzled)
    unsigned short* fwlo = (unsigned short*)alloc(FCOLS * 128 * 2);
    int* row_ptr = (int*)alloc(10004 * 4);
    int* csr     = (int*)alloc(170000 * 4);
    // ---- zero zone (single memset): padded dec W + cnt + cursor ----
    char* zbase = p;
    unsigned short* dwhi = (unsigned short*)alloc(8192 * 2);        // [64,128] padded (swizzled)
    unsigned short* dwlo = (unsigned short*)alloc(8192 * 2);
    int* cnt    = (int*)alloc(10000 * 4);
    int* cursor = (int*)alloc(10000 * 4);
    size_t zbytes = (size_t)(p - zbase);

    hipMemsetAsync(zbase, 0, zbytes, stream);

    // setup: conversions + attention weight rows + biasRG + edge count (one dispatch)
    fused0_k<<<TOT_B, 256, 0, stream>>>(
        x, enc_w, gat_w, res_w, dec_w, att_src, att_dst, res_b, gat_b, ei,
        xhi, xlo, ewhi, ewlo, fwhi, fwlo, dwhi, dwlo, biasRG, cnt);

    // encoder gemm (+ merged CSR prefix scan in last y-slice)
    gemm3_k<1, 2, 1><<<dim3(157, 3), 256, 0, stream>>>(
        xhi, xlo, ewhi, ewlo, enc_b, nullptr, Xhi, Xlo, nullptr, nullptr, NN,
        nullptr, cnt, row_ptr, nullptr, nullptr);

    // layer 1: fused gemm (+ merged fill_csr in last y-slice)
    gemm3_k<2, 1, 2><<<dim3(157, 18), 256, 0, stream>>>(
        Xhi, Xlo, fwhi, fwlo, biasRG, nullptr, xh_b, resb, a_src, a_dst, NN,
        ei, nullptr, row_ptr, cursor, csr);
    agg_k<<<5000, 256, 0, stream>>>(row_ptr, csr, a_src, a_dst, xh_b, resb, Xhi, Xlo);

    // layer 2
    gemm3_k<2, 1, 0><<<dim3(157, 17), 256, 0, stream>>>(
        Xhi, Xlo, fwhi, fwlo, biasRG, nullptr, xh_b, resb, a_src, a_dst, NN,
        nullptr, nullptr, nullptr, nullptr, nullptr);
    agg_k<<<5000, 256, 0, stream>>>(row_ptr, csr, a_src, a_dst, xh_b, resb, Xhi, Xlo);

    // decoder
    gemm3_k<0, 1, 0><<<dim3(157, 1), 256, 0, stream>>>(
        Xhi, Xlo, dwhi, dwlo, dec_b, out, nullptr, nullptr, nullptr, nullptr, NN,
        nullptr, nullptr, nullptr, nullptr, nullptr);
}